// Round 5
// baseline (1162.935 us; speedup 1.0000x reference)
//
#include <hip/hip_runtime.h>
#include <hip/hip_bf16.h>

#define DIM 64
#define NRELS 8
#define NBASES 4
#define NW 9              // 8 relations + self
#define BKT_SHIFT 7
#define BKT_NODES 128     // nodes per bucket
#define MAXBKT 1024
#define P1_CHUNK 2048     // edges per block in count
#define P3_CHUNK 4096     // edges per block in partition
#define EBUF_CAP 2048

typedef __attribute__((ext_vector_type(8))) short short8;
typedef __attribute__((ext_vector_type(4))) float f32x4;

__device__ inline unsigned short f2bf(float f) {
    union { float f; unsigned int u; } v; v.f = f;
    unsigned int u = v.u;
    unsigned int r = u + 0x7FFFu + ((u >> 16) & 1u);  // round-to-nearest-even
    return (unsigned short)(r >> 16);
}
__device__ inline float bf2f(unsigned short s) {
    union { unsigned int u; float f; } v; v.u = ((unsigned int)s) << 16;
    return v.f;
}

// Pack W matrices (8 relation + 1 self) into MFMA B-fragment order, bf16.
// B element for mfma_f32_16x16x32_bf16: k = half*32 + (lane>>4)*8 + e, j = jt*16 + (lane&15)
__global__ void build_wpk(const float* __restrict__ bases, const float* __restrict__ coef,
                          const float* __restrict__ wself, unsigned short* __restrict__ Wpk) {
    int idx = blockIdx.x * blockDim.x + threadIdx.x;
    if (idx >= NW * DIM * DIM) return;
    int r = idx >> 12;
    int k = (idx >> 6) & 63;
    int j = idx & 63;
    float v;
    if (r < NRELS) {
        v = 0.f;
#pragma unroll
        for (int b = 0; b < NBASES; ++b)
            v += coef[r * NBASES + b] * bases[((size_t)b * DIM + k) * DIM + j];
    } else {
        v = wself[k * DIM + j];
    }
    int half = k >> 5, e = k & 7, laneHi = (k >> 3) & 3;
    int jt = j >> 4, laneLo = j & 15;
    int lane = laneHi * 16 + laneLo;
    Wpk[(size_t)((((r * 4 + jt) * 2 + half) * 64 + lane) * 8 + e)] = f2bf(v);
}

// Per 64-node tile (4 waves x 16 nodes):
//   hproj[r][n][:] = bf16( h[n] @ W_r )  (stores coalesced via per-wave LDS tile)
//   outself[n][:]  = h[n] @ wself + bias (f32)
__global__ __launch_bounds__(256) void proj_kernel(const float* __restrict__ h,
                                                   const unsigned short* __restrict__ Wpk,
                                                   const float* __restrict__ bias,
                                                   unsigned short* __restrict__ hproj,
                                                   float* __restrict__ outself, int n_nodes) {
    const int lane = threadIdx.x & 63;
    const int wave = threadIdx.x >> 6;
    const int n0 = blockIdx.x * 64 + wave * 16;
    __shared__ unsigned short tile[4][16][64];  // 8 KB; per-wave private slice
    if (n0 >= n_nodes) return;
    const int lrow = lane & 15;
    const int lhi = lane >> 4;

    int row = n0 + lrow;
    if (row >= n_nodes) row = n_nodes - 1;
    const float* hrow = h + (size_t)row * DIM + lhi * 8;
    float4 x0 = *(const float4*)(hrow);
    float4 x1 = *(const float4*)(hrow + 4);
    float4 x2 = *(const float4*)(hrow + 32);
    float4 x3 = *(const float4*)(hrow + 36);
    short8 a0, a1;
    a0[0] = (short)f2bf(x0.x); a0[1] = (short)f2bf(x0.y);
    a0[2] = (short)f2bf(x0.z); a0[3] = (short)f2bf(x0.w);
    a0[4] = (short)f2bf(x1.x); a0[5] = (short)f2bf(x1.y);
    a0[6] = (short)f2bf(x1.z); a0[7] = (short)f2bf(x1.w);
    a1[0] = (short)f2bf(x2.x); a1[1] = (short)f2bf(x2.y);
    a1[2] = (short)f2bf(x2.z); a1[3] = (short)f2bf(x2.w);
    a1[4] = (short)f2bf(x3.x); a1[5] = (short)f2bf(x3.y);
    a1[6] = (short)f2bf(x3.z); a1[7] = (short)f2bf(x3.w);

    unsigned short (*T)[64] = tile[wave];
    const int rrow = lane >> 2, seg = lane & 3;

    for (int r = 0; r < NW; ++r) {
        f32x4 c[4];
#pragma unroll
        for (int jt = 0; jt < 4; ++jt) {
            const unsigned short* bbase = Wpk + (size_t)(((r * 4 + jt) * 2) * 64 + lane) * 8;
            short8 b0 = *(const short8*)bbase;
            short8 b1 = *(const short8*)(bbase + 512);
            f32x4 cc = {0.f, 0.f, 0.f, 0.f};
            cc = __builtin_amdgcn_mfma_f32_16x16x32_bf16(a0, b0, cc, 0, 0, 0);
            cc = __builtin_amdgcn_mfma_f32_16x16x32_bf16(a1, b1, cc, 0, 0, 0);
            c[jt] = cc;
        }
        if (r < NRELS) {
            // stage 16x64 bf16 tile in wave-private LDS, then coalesced dwordx4 stores
#pragma unroll
            for (int jt = 0; jt < 4; ++jt)
#pragma unroll
                for (int reg = 0; reg < 4; ++reg)
                    T[lhi * 4 + reg][jt * 16 + lrow] = f2bf(c[jt][reg]);
            float4 lo = *(const float4*)&T[rrow][seg * 16];
            float4 hi = *(const float4*)&T[rrow][seg * 16 + 8];
            if (n0 + rrow < n_nodes) {
                float4* dp = (float4*)(hproj + ((size_t)r * n_nodes + n0 + rrow) * DIM + seg * 16);
                dp[0] = lo;
                dp[1] = hi;
            }
        } else {
            // self path: f32 stores are full-64B-segment coalesced already
#pragma unroll
            for (int jt = 0; jt < 4; ++jt) {
                int j = jt * 16 + lrow;
                float bj = bias[j];
                float* op = outself + (size_t)n0 * DIM + j;
#pragma unroll
                for (int reg = 0; reg < 4; ++reg) {
                    int i = lhi * 4 + reg;
                    if (n0 + i < n_nodes) op[(size_t)i * DIM] = c[jt][reg] + bj;
                }
            }
        }
    }
}

// ---- bucket partition (replaces hist/scan/reorder CSR) ----

__global__ __launch_bounds__(256) void bucket_count(const int* __restrict__ dst,
                                                    int* __restrict__ bktcnt,
                                                    int n_edges, int nbkt) {
    __shared__ int h[MAXBKT];
    int t = threadIdx.x;
    for (int i = t; i < nbkt; i += 256) h[i] = 0;
    __syncthreads();
    int e0 = blockIdx.x * P1_CHUNK;
#pragma unroll
    for (int k = 0; k < P1_CHUNK / 256; ++k) {
        int e = e0 + k * 256 + t;
        if (e < n_edges) atomicAdd(&h[dst[e] >> BKT_SHIFT], 1);
    }
    __syncthreads();
    for (int i = t; i < nbkt; i += 256)
        if (h[i]) atomicAdd(&bktcnt[i], h[i]);
}

__global__ __launch_bounds__(1024) void scan_bkt(const int* __restrict__ cnt,
                                                 int* __restrict__ off,
                                                 int* __restrict__ pos, int nbkt) {
    __shared__ int a[1024], b[1024];
    int t = threadIdx.x;
    int v = (t < nbkt) ? cnt[t] : 0;
    a[t] = v;
    __syncthreads();
    int* pin = a;
    int* pout = b;
    for (int d = 1; d < 1024; d <<= 1) {
        pout[t] = pin[t] + ((t >= d) ? pin[t - d] : 0);
        __syncthreads();
        int* tmp = pin; pin = pout; pout = tmp;
    }
    int incl = pin[t];
    int excl = incl - v;
    if (t < nbkt) { off[t] = excl; pos[t] = excl; }
    if (t == 1023) off[nbkt] = incl;
}

__global__ __launch_bounds__(256) void partition(const int* __restrict__ src,
                                                 const int* __restrict__ dst,
                                                 const int* __restrict__ et,
                                                 int* __restrict__ bktpos,
                                                 unsigned* __restrict__ perm,
                                                 int n_edges, int nbkt) {
    __shared__ int h[MAXBKT];
    __shared__ int base[MAXBKT];
    int t = threadIdx.x;
    for (int i = t; i < nbkt; i += 256) h[i] = 0;
    __syncthreads();
    int e0 = blockIdx.x * P3_CHUNK;
#pragma unroll
    for (int k = 0; k < P3_CHUNK / 256; ++k) {
        int e = e0 + k * 256 + t;
        if (e < n_edges) atomicAdd(&h[dst[e] >> BKT_SHIFT], 1);
    }
    __syncthreads();
    for (int i = t; i < nbkt; i += 256) {
        int c = h[i];
        base[i] = c ? atomicAdd(&bktpos[i], c) : 0;
        h[i] = 0;
    }
    __syncthreads();
#pragma unroll
    for (int k = 0; k < P3_CHUNK / 256; ++k) {
        int e = e0 + k * 256 + t;
        if (e < n_edges) {
            int d = dst[e];
            int bk = d >> BKT_SHIFT;
            int rk = atomicAdd(&h[bk], 1);
            perm[base[bk] + rk] =
                (unsigned)src[e] | ((unsigned)et[e] << 17) | ((unsigned)(d & (BKT_NODES - 1)) << 20);
        }
    }
}

// gather2: one block per bucket; LDS f32 accumulator over the bucket's 128 nodes.
__global__ __launch_bounds__(256) void gather2(const unsigned* __restrict__ perm,
                                               const int* __restrict__ bktoff,
                                               const unsigned short* __restrict__ hproj,
                                               float* __restrict__ out, int n_nodes) {
    __shared__ float acc[BKT_NODES * DIM];  // 32 KB
    __shared__ unsigned ebuf[EBUF_CAP];     // 8 KB
    const int t = threadIdx.x;
    const int lane = t & 63;
    const int wave = t >> 6;
    const int b = blockIdx.x;
    const int beg = bktoff[b], end = bktoff[b + 1];
    if (beg == end) return;
    const int n0 = b * BKT_NODES;
    const int nrows = min(BKT_NODES, n_nodes - n0);

    for (int i = t; i < BKT_NODES * DIM; i += 256) acc[i] = 0.f;

    const size_t nn = (size_t)n_nodes;
    for (int cbeg = beg; cbeg < end; cbeg += EBUF_CAP) {
        int cnt = min(EBUF_CAP, end - cbeg);
        __syncthreads();
        for (int i = t; i < cnt; i += 256) ebuf[i] = perm[cbeg + i];
        __syncthreads();
        int j = wave;
        for (; j + 28 < cnt; j += 32) {
            unsigned r0 = ebuf[j], r1 = ebuf[j + 4], r2 = ebuf[j + 8], r3 = ebuf[j + 12];
            unsigned r4 = ebuf[j + 16], r5 = ebuf[j + 20], r6 = ebuf[j + 24], r7 = ebuf[j + 28];
            float v0 = bf2f(hproj[(((size_t)((r0 >> 17) & 7)) * nn + (r0 & 0x1FFFFu)) * DIM + lane]);
            float v1 = bf2f(hproj[(((size_t)((r1 >> 17) & 7)) * nn + (r1 & 0x1FFFFu)) * DIM + lane]);
            float v2 = bf2f(hproj[(((size_t)((r2 >> 17) & 7)) * nn + (r2 & 0x1FFFFu)) * DIM + lane]);
            float v3 = bf2f(hproj[(((size_t)((r3 >> 17) & 7)) * nn + (r3 & 0x1FFFFu)) * DIM + lane]);
            float v4 = bf2f(hproj[(((size_t)((r4 >> 17) & 7)) * nn + (r4 & 0x1FFFFu)) * DIM + lane]);
            float v5 = bf2f(hproj[(((size_t)((r5 >> 17) & 7)) * nn + (r5 & 0x1FFFFu)) * DIM + lane]);
            float v6 = bf2f(hproj[(((size_t)((r6 >> 17) & 7)) * nn + (r6 & 0x1FFFFu)) * DIM + lane]);
            float v7 = bf2f(hproj[(((size_t)((r7 >> 17) & 7)) * nn + (r7 & 0x1FFFFu)) * DIM + lane]);
            atomicAdd(&acc[(r0 >> 20) * DIM + lane], v0);
            atomicAdd(&acc[(r1 >> 20) * DIM + lane], v1);
            atomicAdd(&acc[(r2 >> 20) * DIM + lane], v2);
            atomicAdd(&acc[(r3 >> 20) * DIM + lane], v3);
            atomicAdd(&acc[(r4 >> 20) * DIM + lane], v4);
            atomicAdd(&acc[(r5 >> 20) * DIM + lane], v5);
            atomicAdd(&acc[(r6 >> 20) * DIM + lane], v6);
            atomicAdd(&acc[(r7 >> 20) * DIM + lane], v7);
        }
        for (; j < cnt; j += 4) {
            unsigned rc = ebuf[j];
            float v = bf2f(hproj[(((size_t)((rc >> 17) & 7)) * nn + (rc & 0x1FFFFu)) * DIM + lane]);
            atomicAdd(&acc[(rc >> 20) * DIM + lane], v);
        }
    }
    __syncthreads();
    float* ob = out + (size_t)n0 * DIM;
    for (int i = t; i < nrows * DIM; i += 256) ob[i] += acc[i];
}

extern "C" void kernel_launch(void* const* d_in, const int* in_sizes, int n_in,
                              void* d_out, int out_size, void* d_ws, size_t ws_size,
                              hipStream_t stream) {
    const int* src = (const int*)d_in[0];
    const int* dst = (const int*)d_in[1];
    const int* et  = (const int*)d_in[2];
    const float* emb    = (const float*)d_in[3];
    const float* bases1 = (const float*)d_in[4];
    const float* coef1  = (const float*)d_in[5];
    const float* wself1 = (const float*)d_in[6];
    const float* bias1  = (const float*)d_in[7];
    const float* bases2 = (const float*)d_in[8];
    const float* coef2  = (const float*)d_in[9];
    const float* wself2 = (const float*)d_in[10];
    const float* bias2  = (const float*)d_in[11];
    float* out = (float*)d_out;

    const int NE = in_sizes[0];
    const int NN = in_sizes[3] / DIM;
    const int NBKT = (NN + BKT_NODES - 1) / BKT_NODES;  // 782 for NN=100000

    // Workspace: Wpk1 | Wpk2 | h1 | hproj | bktcnt | bktoff | bktpos | perm  (~133 MB)
    unsigned short* Wpk1 = (unsigned short*)d_ws;
    unsigned short* Wpk2 = Wpk1 + (size_t)NW * DIM * DIM;
    float* h1 = (float*)(Wpk2 + (size_t)NW * DIM * DIM);
    unsigned short* hproj = (unsigned short*)(h1 + (size_t)NN * DIM);
    int* bktcnt = (int*)(hproj + (size_t)NRELS * NN * DIM);
    int* bktoff = bktcnt + MAXBKT;
    int* bktpos = bktoff + MAXBKT + 1;
    unsigned* perm = (unsigned*)(bktpos + MAXBKT);

    const int wpk_threads = NW * DIM * DIM;
    build_wpk<<<(wpk_threads + 255) / 256, 256, 0, stream>>>(bases1, coef1, wself1, Wpk1);
    build_wpk<<<(wpk_threads + 255) / 256, 256, 0, stream>>>(bases2, coef2, wself2, Wpk2);

    hipMemsetAsync(bktcnt, 0, (size_t)NBKT * 4, stream);
    bucket_count<<<(NE + P1_CHUNK - 1) / P1_CHUNK, 256, 0, stream>>>(dst, bktcnt, NE, NBKT);
    scan_bkt<<<1, 1024, 0, stream>>>(bktcnt, bktoff, bktpos, NBKT);
    partition<<<(NE + P3_CHUNK - 1) / P3_CHUNK, 256, 0, stream>>>(src, dst, et, bktpos, perm, NE, NBKT);

    const int proj_blocks = (NN + 63) / 64;

    // Layer 1
    proj_kernel<<<proj_blocks, 256, 0, stream>>>(emb, Wpk1, bias1, hproj, h1, NN);
    gather2<<<NBKT, 256, 0, stream>>>(perm, bktoff, hproj, h1, NN);

    // Layer 2
    proj_kernel<<<proj_blocks, 256, 0, stream>>>(h1, Wpk2, bias2, hproj, out, NN);
    gather2<<<NBKT, 256, 0, stream>>>(perm, bktoff, hproj, out, NN);
}

// Round 6
// 238.278 us; speedup vs baseline: 4.8806x; 4.8806x over previous
//
#include <hip/hip_runtime.h>
#include <hip/hip_bf16.h>

#define DIM 64
#define NRELS 8
#define NBASES 4
#define NW 9              // 8 relations + self
#define BKT_SHIFT 7
#define BKT_NODES 128     // nodes per bucket
#define MAXBKT 1024
#define P1_CHUNK 2048
#define P3_CHUNK 4096

typedef __attribute__((ext_vector_type(8))) short short8;
typedef __attribute__((ext_vector_type(4))) float f32x4;

__device__ inline unsigned short f2bf(float f) {
    union { float f; unsigned int u; } v; v.f = f;
    unsigned int u = v.u;
    unsigned int r = u + 0x7FFFu + ((u >> 16) & 1u);  // round-to-nearest-even
    return (unsigned short)(r >> 16);
}
__device__ inline float bf2f(unsigned short s) {
    union { unsigned int u; float f; } v; v.u = ((unsigned int)s) << 16;
    return v.f;
}

// Pack W matrices (8 relation + 1 self) into MFMA B-fragment order, bf16.
__global__ void build_wpk(const float* __restrict__ bases, const float* __restrict__ coef,
                          const float* __restrict__ wself, unsigned short* __restrict__ Wpk) {
    int idx = blockIdx.x * blockDim.x + threadIdx.x;
    if (idx >= NW * DIM * DIM) return;
    int r = idx >> 12;
    int k = (idx >> 6) & 63;
    int j = idx & 63;
    float v;
    if (r < NRELS) {
        v = 0.f;
#pragma unroll
        for (int b = 0; b < NBASES; ++b)
            v += coef[r * NBASES + b] * bases[((size_t)b * DIM + k) * DIM + j];
    } else {
        v = wself[k * DIM + j];
    }
    int half = k >> 5, e = k & 7, laneHi = (k >> 3) & 3;
    int jt = j >> 4, laneLo = j & 15;
    int lane = laneHi * 16 + laneLo;
    Wpk[(size_t)((((r * 4 + jt) * 2 + half) * 64 + lane) * 8 + e)] = f2bf(v);
}

// Per 64-node tile (4 waves x 16 nodes):
//   hproj[r][n][:] = bf16( h[n] @ W_r ),  selfbuf[n][:] = h[n] @ wself + bias (f32)
__global__ __launch_bounds__(256) void proj_kernel(const float* __restrict__ h,
                                                   const unsigned short* __restrict__ Wpk,
                                                   const float* __restrict__ bias,
                                                   unsigned short* __restrict__ hproj,
                                                   float* __restrict__ selfbuf, int n_nodes) {
    const int lane = threadIdx.x & 63;
    const int wave = threadIdx.x >> 6;
    const int n0 = blockIdx.x * 64 + wave * 16;
    __shared__ unsigned short tile[4][16][64];  // 8 KB; per-wave private slice
    if (n0 >= n_nodes) return;
    const int lrow = lane & 15;
    const int lhi = lane >> 4;

    int row = n0 + lrow;
    if (row >= n_nodes) row = n_nodes - 1;
    const float* hrow = h + (size_t)row * DIM + lhi * 8;
    float4 x0 = *(const float4*)(hrow);
    float4 x1 = *(const float4*)(hrow + 4);
    float4 x2 = *(const float4*)(hrow + 32);
    float4 x3 = *(const float4*)(hrow + 36);
    short8 a0, a1;
    a0[0] = (short)f2bf(x0.x); a0[1] = (short)f2bf(x0.y);
    a0[2] = (short)f2bf(x0.z); a0[3] = (short)f2bf(x0.w);
    a0[4] = (short)f2bf(x1.x); a0[5] = (short)f2bf(x1.y);
    a0[6] = (short)f2bf(x1.z); a0[7] = (short)f2bf(x1.w);
    a1[0] = (short)f2bf(x2.x); a1[1] = (short)f2bf(x2.y);
    a1[2] = (short)f2bf(x2.z); a1[3] = (short)f2bf(x2.w);
    a1[4] = (short)f2bf(x3.x); a1[5] = (short)f2bf(x3.y);
    a1[6] = (short)f2bf(x3.z); a1[7] = (short)f2bf(x3.w);

    unsigned short (*T)[64] = tile[wave];
    const int rrow = lane >> 2, seg = lane & 3;

    for (int r = 0; r < NW; ++r) {
        f32x4 c[4];
#pragma unroll
        for (int jt = 0; jt < 4; ++jt) {
            const unsigned short* bbase = Wpk + (size_t)(((r * 4 + jt) * 2) * 64 + lane) * 8;
            short8 b0 = *(const short8*)bbase;
            short8 b1 = *(const short8*)(bbase + 512);
            f32x4 cc = {0.f, 0.f, 0.f, 0.f};
            cc = __builtin_amdgcn_mfma_f32_16x16x32_bf16(a0, b0, cc, 0, 0, 0);
            cc = __builtin_amdgcn_mfma_f32_16x16x32_bf16(a1, b1, cc, 0, 0, 0);
            c[jt] = cc;
        }
        if (r < NRELS) {
#pragma unroll
            for (int jt = 0; jt < 4; ++jt)
#pragma unroll
                for (int reg = 0; reg < 4; ++reg)
                    T[lhi * 4 + reg][jt * 16 + lrow] = f2bf(c[jt][reg]);
            float4 lo = *(const float4*)&T[rrow][seg * 16];
            float4 hi = *(const float4*)&T[rrow][seg * 16 + 8];
            if (n0 + rrow < n_nodes) {
                float4* dp = (float4*)(hproj + ((size_t)r * n_nodes + n0 + rrow) * DIM + seg * 16);
                dp[0] = lo;
                dp[1] = hi;
            }
        } else {
#pragma unroll
            for (int jt = 0; jt < 4; ++jt) {
                int j = jt * 16 + lrow;
                float bj = bias[j];
                float* op = selfbuf + (size_t)n0 * DIM + j;
#pragma unroll
                for (int reg = 0; reg < 4; ++reg) {
                    int i = lhi * 4 + reg;
                    if (n0 + i < n_nodes) op[(size_t)i * DIM] = c[jt][reg] + bj;
                }
            }
        }
    }
}

// ---- two-level CSR build ----

__global__ __launch_bounds__(256) void bucket_count(const int* __restrict__ dst,
                                                    int* __restrict__ bktcnt,
                                                    int n_edges, int nbkt) {
    __shared__ int h[MAXBKT];
    int t = threadIdx.x;
    for (int i = t; i < nbkt; i += 256) h[i] = 0;
    __syncthreads();
    int e0 = blockIdx.x * P1_CHUNK;
#pragma unroll
    for (int k = 0; k < P1_CHUNK / 256; ++k) {
        int e = e0 + k * 256 + t;
        if (e < n_edges) atomicAdd(&h[dst[e] >> BKT_SHIFT], 1);
    }
    __syncthreads();
    for (int i = t; i < nbkt; i += 256)
        if (h[i]) atomicAdd(&bktcnt[i], h[i]);
}

__global__ __launch_bounds__(1024) void scan_bkt(const int* __restrict__ cnt,
                                                 int* __restrict__ off,
                                                 int* __restrict__ pos, int nbkt) {
    __shared__ int a[1024], b[1024];
    int t = threadIdx.x;
    int v = (t < nbkt) ? cnt[t] : 0;
    a[t] = v;
    __syncthreads();
    int* pin = a;
    int* pout = b;
    for (int d = 1; d < 1024; d <<= 1) {
        pout[t] = pin[t] + ((t >= d) ? pin[t - d] : 0);
        __syncthreads();
        int* tmp = pin; pin = pout; pout = tmp;
    }
    int incl = pin[t];
    int excl = incl - v;
    if (t < nbkt) { off[t] = excl; pos[t] = excl; }
    if (t == 1023) off[nbkt] = incl;
}

// Partition edges into bucket-contiguous perm_tmp, packed src | et<<17 | dstlow<<20
__global__ __launch_bounds__(256) void partition(const int* __restrict__ src,
                                                 const int* __restrict__ dst,
                                                 const int* __restrict__ et,
                                                 int* __restrict__ bktpos,
                                                 unsigned* __restrict__ perm_tmp,
                                                 int n_edges, int nbkt) {
    __shared__ int h[MAXBKT];
    __shared__ int base[MAXBKT];
    int t = threadIdx.x;
    for (int i = t; i < nbkt; i += 256) h[i] = 0;
    __syncthreads();
    int e0 = blockIdx.x * P3_CHUNK;
#pragma unroll
    for (int k = 0; k < P3_CHUNK / 256; ++k) {
        int e = e0 + k * 256 + t;
        if (e < n_edges) atomicAdd(&h[dst[e] >> BKT_SHIFT], 1);
    }
    __syncthreads();
    for (int i = t; i < nbkt; i += 256) {
        int c = h[i];
        base[i] = c ? atomicAdd(&bktpos[i], c) : 0;
        h[i] = 0;
    }
    __syncthreads();
#pragma unroll
    for (int k = 0; k < P3_CHUNK / 256; ++k) {
        int e = e0 + k * 256 + t;
        if (e < n_edges) {
            int d = dst[e];
            int bk = d >> BKT_SHIFT;
            int rk = atomicAdd(&h[bk], 1);
            perm_tmp[base[bk] + rk] =
                (unsigned)src[e] | ((unsigned)et[e] << 17) | ((unsigned)(d & (BKT_NODES - 1)) << 20);
        }
    }
}

// One block per bucket: exact per-dst CSR. Emits doff[] and dst-sorted perm (src|et, 20 bits).
__global__ __launch_bounds__(256) void bucket_csr(const unsigned* __restrict__ perm_tmp,
                                                  const int* __restrict__ bktoff,
                                                  unsigned* __restrict__ perm,
                                                  int* __restrict__ doff, int n_nodes) {
    __shared__ int h[BKT_NODES];
    __shared__ int sa[BKT_NODES], sb[BKT_NODES];
    __shared__ int lpos[BKT_NODES];
    const int t = threadIdx.x;
    const int b = blockIdx.x;
    const int beg = bktoff[b], end = bktoff[b + 1];
    if (t < BKT_NODES) h[t] = 0;
    __syncthreads();
    for (int i = beg + t; i < end; i += 256) atomicAdd(&h[perm_tmp[i] >> 20], 1);
    __syncthreads();
    int v = (t < BKT_NODES) ? h[t] : 0;
    if (t < BKT_NODES) sa[t] = v;
    __syncthreads();
    int* pin = sa;
    int* pout = sb;
    for (int d = 1; d < BKT_NODES; d <<= 1) {
        if (t < BKT_NODES) pout[t] = pin[t] + ((t >= d) ? pin[t - d] : 0);
        __syncthreads();
        int* tmp = pin; pin = pout; pout = tmp;
    }
    if (t < BKT_NODES) {
        int excl = pin[t] - v;
        lpos[t] = beg + excl;
        int dnode = b * BKT_NODES + t;
        if (dnode < n_nodes) doff[dnode] = beg + excl;
    }
    if (b == gridDim.x - 1 && t == 0) doff[n_nodes] = end;
    __syncthreads();
    for (int i = beg + t; i < end; i += 256) {
        unsigned rc = perm_tmp[i];
        int p = atomicAdd(&lpos[rc >> 20], 1);
        perm[p] = rc & 0xFFFFFu;  // src | et<<17
    }
}

// gather3: one wave per dst. half 0/1 = even/odd edges; lane covers a col-pair via ushort2.
__global__ __launch_bounds__(256) void gather3(const unsigned* __restrict__ perm,
                                               const int* __restrict__ doff,
                                               const unsigned short* __restrict__ hproj,
                                               const float* __restrict__ selfbuf,
                                               float* __restrict__ out, int n_nodes) {
    int gid = blockIdx.x * blockDim.x + threadIdx.x;
    int d = gid >> 6;
    if (d >= n_nodes) return;
    int lane = gid & 63;
    int half = lane >> 5, hl = lane & 31;
    int beg = doff[d], end = doff[d + 1];
    const size_t nn = (size_t)n_nodes;
    float ax = 0.f, ay = 0.f;
    int i = beg + half;
    for (; i + 6 < end; i += 8) {
        unsigned rc0 = perm[i], rc1 = perm[i + 2], rc2 = perm[i + 4], rc3 = perm[i + 6];
        unsigned v0 = *(const unsigned*)(hproj + ((size_t)(rc0 >> 17) * nn + (rc0 & 0x1FFFFu)) * DIM + 2 * hl);
        unsigned v1 = *(const unsigned*)(hproj + ((size_t)(rc1 >> 17) * nn + (rc1 & 0x1FFFFu)) * DIM + 2 * hl);
        unsigned v2 = *(const unsigned*)(hproj + ((size_t)(rc2 >> 17) * nn + (rc2 & 0x1FFFFu)) * DIM + 2 * hl);
        unsigned v3 = *(const unsigned*)(hproj + ((size_t)(rc3 >> 17) * nn + (rc3 & 0x1FFFFu)) * DIM + 2 * hl);
        ax += bf2f((unsigned short)(v0 & 0xFFFFu)); ay += bf2f((unsigned short)(v0 >> 16));
        ax += bf2f((unsigned short)(v1 & 0xFFFFu)); ay += bf2f((unsigned short)(v1 >> 16));
        ax += bf2f((unsigned short)(v2 & 0xFFFFu)); ay += bf2f((unsigned short)(v2 >> 16));
        ax += bf2f((unsigned short)(v3 & 0xFFFFu)); ay += bf2f((unsigned short)(v3 >> 16));
    }
    for (; i < end; i += 2) {
        unsigned rc = perm[i];
        unsigned v = *(const unsigned*)(hproj + ((size_t)(rc >> 17) * nn + (rc & 0x1FFFFu)) * DIM + 2 * hl);
        ax += bf2f((unsigned short)(v & 0xFFFFu)); ay += bf2f((unsigned short)(v >> 16));
    }
    // merge even/odd halves: lane l and l^32 hold same col-pair
    ax += __shfl_xor(ax, 32);
    ay += __shfl_xor(ay, 32);
    if (half == 0) {
        const float2 s = *(const float2*)(selfbuf + (size_t)d * DIM + 2 * hl);
        float2 o; o.x = ax + s.x; o.y = ay + s.y;
        *(float2*)(out + (size_t)d * DIM + 2 * hl) = o;
    }
}

extern "C" void kernel_launch(void* const* d_in, const int* in_sizes, int n_in,
                              void* d_out, int out_size, void* d_ws, size_t ws_size,
                              hipStream_t stream) {
    const int* src = (const int*)d_in[0];
    const int* dst = (const int*)d_in[1];
    const int* et  = (const int*)d_in[2];
    const float* emb    = (const float*)d_in[3];
    const float* bases1 = (const float*)d_in[4];
    const float* coef1  = (const float*)d_in[5];
    const float* wself1 = (const float*)d_in[6];
    const float* bias1  = (const float*)d_in[7];
    const float* bases2 = (const float*)d_in[8];
    const float* coef2  = (const float*)d_in[9];
    const float* wself2 = (const float*)d_in[10];
    const float* bias2  = (const float*)d_in[11];
    float* out = (float*)d_out;

    const int NE = in_sizes[0];
    const int NN = in_sizes[3] / DIM;
    const int NBKT = (NN + BKT_NODES - 1) / BKT_NODES;  // 782

    // Workspace: Wpk1|Wpk2|selfbuf|h1|hproj|bktcnt|bktoff|bktpos|doff|perm_tmp|perm  (~164 MB)
    unsigned short* Wpk1 = (unsigned short*)d_ws;
    unsigned short* Wpk2 = Wpk1 + (size_t)NW * DIM * DIM;
    float* selfbuf = (float*)(Wpk2 + (size_t)NW * DIM * DIM);
    float* h1 = selfbuf + (size_t)NN * DIM;
    unsigned short* hproj = (unsigned short*)(h1 + (size_t)NN * DIM);
    int* bktcnt = (int*)(hproj + (size_t)NRELS * NN * DIM);
    int* bktoff = bktcnt + MAXBKT;
    int* bktpos = bktoff + MAXBKT + 1;
    int* doff = bktpos + MAXBKT;
    unsigned* perm_tmp = (unsigned*)(doff + NN + 64);
    unsigned* perm = perm_tmp + NE;

    const int wpk_threads = NW * DIM * DIM;
    build_wpk<<<(wpk_threads + 255) / 256, 256, 0, stream>>>(bases1, coef1, wself1, Wpk1);
    build_wpk<<<(wpk_threads + 255) / 256, 256, 0, stream>>>(bases2, coef2, wself2, Wpk2);

    hipMemsetAsync(bktcnt, 0, (size_t)NBKT * 4, stream);
    bucket_count<<<(NE + P1_CHUNK - 1) / P1_CHUNK, 256, 0, stream>>>(dst, bktcnt, NE, NBKT);
    scan_bkt<<<1, 1024, 0, stream>>>(bktcnt, bktoff, bktpos, NBKT);
    partition<<<(NE + P3_CHUNK - 1) / P3_CHUNK, 256, 0, stream>>>(src, dst, et, bktpos, perm_tmp, NE, NBKT);
    bucket_csr<<<NBKT, 256, 0, stream>>>(perm_tmp, bktoff, perm, doff, NN);

    const int proj_blocks = (NN + 63) / 64;
    const int gath_blocks = (NN + 3) / 4;  // one wave per dst

    // Layer 1
    proj_kernel<<<proj_blocks, 256, 0, stream>>>(emb, Wpk1, bias1, hproj, selfbuf, NN);
    gather3<<<gath_blocks, 256, 0, stream>>>(perm, doff, hproj, selfbuf, h1, NN);

    // Layer 2
    proj_kernel<<<proj_blocks, 256, 0, stream>>>(h1, Wpk2, bias2, hproj, selfbuf, NN);
    gather3<<<gath_blocks, 256, 0, stream>>>(perm, doff, hproj, selfbuf, out, NN);
}

// Round 7
// 224.859 us; speedup vs baseline: 5.1718x; 1.0597x over previous
//
#include <hip/hip_runtime.h>
#include <hip/hip_bf16.h>

#define DIM 64
#define NRELS 8
#define NBASES 4
#define NW 9              // 8 relations + self
#define BKT_SHIFT 7
#define BKT_NODES 128     // nodes per bucket
#define MAXBKT 1024
#define P1_CHUNK 2048
#define P3_CHUNK 4096

typedef __attribute__((ext_vector_type(8))) short short8;
typedef __attribute__((ext_vector_type(4))) float f32x4;

__device__ inline unsigned short f2bf(float f) {
    union { float f; unsigned int u; } v; v.f = f;
    unsigned int u = v.u;
    unsigned int r = u + 0x7FFFu + ((u >> 16) & 1u);  // round-to-nearest-even
    return (unsigned short)(r >> 16);
}
__device__ inline float bf2f(unsigned short s) {
    union { unsigned int u; float f; } v; v.u = ((unsigned int)s) << 16;
    return v.f;
}

// Pack W matrices (8 relation + 1 self) into MFMA B-fragment order, bf16.
__global__ void build_wpk(const float* __restrict__ bases, const float* __restrict__ coef,
                          const float* __restrict__ wself, unsigned short* __restrict__ Wpk) {
    int idx = blockIdx.x * blockDim.x + threadIdx.x;
    if (idx >= NW * DIM * DIM) return;
    int r = idx >> 12;
    int k = (idx >> 6) & 63;
    int j = idx & 63;
    float v;
    if (r < NRELS) {
        v = 0.f;
#pragma unroll
        for (int b = 0; b < NBASES; ++b)
            v += coef[r * NBASES + b] * bases[((size_t)b * DIM + k) * DIM + j];
    } else {
        v = wself[k * DIM + j];
    }
    int half = k >> 5, e = k & 7, laneHi = (k >> 3) & 3;
    int jt = j >> 4, laneLo = j & 15;
    int lane = laneHi * 16 + laneLo;
    Wpk[(size_t)((((r * 4 + jt) * 2 + half) * 64 + lane) * 8 + e)] = f2bf(v);
}

// Per 64-node tile (4 waves x 16 nodes):
//   hproj[r][n][:] = bf16( h[n] @ W_r ),  selfbuf[n][:] = h[n] @ wself + bias (f32)
__global__ __launch_bounds__(256) void proj_kernel(const float* __restrict__ h,
                                                   const unsigned short* __restrict__ Wpk,
                                                   const float* __restrict__ bias,
                                                   unsigned short* __restrict__ hproj,
                                                   float* __restrict__ selfbuf, int n_nodes) {
    const int lane = threadIdx.x & 63;
    const int wave = threadIdx.x >> 6;
    const int n0 = blockIdx.x * 64 + wave * 16;
    __shared__ unsigned short tile[4][16][64];  // 8 KB; per-wave private slice
    if (n0 >= n_nodes) return;
    const int lrow = lane & 15;
    const int lhi = lane >> 4;

    int row = n0 + lrow;
    if (row >= n_nodes) row = n_nodes - 1;
    const float* hrow = h + (size_t)row * DIM + lhi * 8;
    float4 x0 = *(const float4*)(hrow);
    float4 x1 = *(const float4*)(hrow + 4);
    float4 x2 = *(const float4*)(hrow + 32);
    float4 x3 = *(const float4*)(hrow + 36);
    short8 a0, a1;
    a0[0] = (short)f2bf(x0.x); a0[1] = (short)f2bf(x0.y);
    a0[2] = (short)f2bf(x0.z); a0[3] = (short)f2bf(x0.w);
    a0[4] = (short)f2bf(x1.x); a0[5] = (short)f2bf(x1.y);
    a0[6] = (short)f2bf(x1.z); a0[7] = (short)f2bf(x1.w);
    a1[0] = (short)f2bf(x2.x); a1[1] = (short)f2bf(x2.y);
    a1[2] = (short)f2bf(x2.z); a1[3] = (short)f2bf(x2.w);
    a1[4] = (short)f2bf(x3.x); a1[5] = (short)f2bf(x3.y);
    a1[6] = (short)f2bf(x3.z); a1[7] = (short)f2bf(x3.w);

    unsigned short (*T)[64] = tile[wave];
    const int rrow = lane >> 2, seg = lane & 3;

    for (int r = 0; r < NW; ++r) {
        f32x4 c[4];
#pragma unroll
        for (int jt = 0; jt < 4; ++jt) {
            const unsigned short* bbase = Wpk + (size_t)(((r * 4 + jt) * 2) * 64 + lane) * 8;
            short8 b0 = *(const short8*)bbase;
            short8 b1 = *(const short8*)(bbase + 512);
            f32x4 cc = {0.f, 0.f, 0.f, 0.f};
            cc = __builtin_amdgcn_mfma_f32_16x16x32_bf16(a0, b0, cc, 0, 0, 0);
            cc = __builtin_amdgcn_mfma_f32_16x16x32_bf16(a1, b1, cc, 0, 0, 0);
            c[jt] = cc;
        }
        if (r < NRELS) {
#pragma unroll
            for (int jt = 0; jt < 4; ++jt)
#pragma unroll
                for (int reg = 0; reg < 4; ++reg)
                    T[lhi * 4 + reg][jt * 16 + lrow] = f2bf(c[jt][reg]);
            float4 lo = *(const float4*)&T[rrow][seg * 16];
            float4 hi = *(const float4*)&T[rrow][seg * 16 + 8];
            if (n0 + rrow < n_nodes) {
                float4* dp = (float4*)(hproj + ((size_t)r * n_nodes + n0 + rrow) * DIM + seg * 16);
                dp[0] = lo;
                dp[1] = hi;
            }
        } else {
#pragma unroll
            for (int jt = 0; jt < 4; ++jt) {
                int j = jt * 16 + lrow;
                float bj = bias[j];
                float* op = selfbuf + (size_t)n0 * DIM + j;
#pragma unroll
                for (int reg = 0; reg < 4; ++reg) {
                    int i = lhi * 4 + reg;
                    if (n0 + i < n_nodes) op[(size_t)i * DIM] = c[jt][reg] + bj;
                }
            }
        }
    }
}

// ---- two-level CSR build ----

__global__ __launch_bounds__(256) void bucket_count(const int* __restrict__ dst,
                                                    int* __restrict__ bktcnt,
                                                    int n_edges, int nbkt) {
    __shared__ int h[MAXBKT];
    int t = threadIdx.x;
    for (int i = t; i < nbkt; i += 256) h[i] = 0;
    __syncthreads();
    int e0 = blockIdx.x * P1_CHUNK;
#pragma unroll
    for (int k = 0; k < P1_CHUNK / 256; ++k) {
        int e = e0 + k * 256 + t;
        if (e < n_edges) atomicAdd(&h[dst[e] >> BKT_SHIFT], 1);
    }
    __syncthreads();
    for (int i = t; i < nbkt; i += 256)
        if (h[i]) atomicAdd(&bktcnt[i], h[i]);
}

__global__ __launch_bounds__(1024) void scan_bkt(const int* __restrict__ cnt,
                                                 int* __restrict__ off,
                                                 int* __restrict__ pos, int nbkt) {
    __shared__ int a[1024], b[1024];
    int t = threadIdx.x;
    int v = (t < nbkt) ? cnt[t] : 0;
    a[t] = v;
    __syncthreads();
    int* pin = a;
    int* pout = b;
    for (int d = 1; d < 1024; d <<= 1) {
        pout[t] = pin[t] + ((t >= d) ? pin[t - d] : 0);
        __syncthreads();
        int* tmp = pin; pin = pout; pout = tmp;
    }
    int incl = pin[t];
    int excl = incl - v;
    if (t < nbkt) { off[t] = excl; pos[t] = excl; }
    if (t == 1023) off[nbkt] = incl;
}

// Partition edges into bucket-contiguous perm_tmp, packed src | et<<17 | dstlow<<20
__global__ __launch_bounds__(256) void partition(const int* __restrict__ src,
                                                 const int* __restrict__ dst,
                                                 const int* __restrict__ et,
                                                 int* __restrict__ bktpos,
                                                 unsigned* __restrict__ perm_tmp,
                                                 int n_edges, int nbkt) {
    __shared__ int h[MAXBKT];
    __shared__ int base[MAXBKT];
    int t = threadIdx.x;
    for (int i = t; i < nbkt; i += 256) h[i] = 0;
    __syncthreads();
    int e0 = blockIdx.x * P3_CHUNK;
#pragma unroll
    for (int k = 0; k < P3_CHUNK / 256; ++k) {
        int e = e0 + k * 256 + t;
        if (e < n_edges) atomicAdd(&h[dst[e] >> BKT_SHIFT], 1);
    }
    __syncthreads();
    for (int i = t; i < nbkt; i += 256) {
        int c = h[i];
        base[i] = c ? atomicAdd(&bktpos[i], c) : 0;
        h[i] = 0;
    }
    __syncthreads();
#pragma unroll
    for (int k = 0; k < P3_CHUNK / 256; ++k) {
        int e = e0 + k * 256 + t;
        if (e < n_edges) {
            int d = dst[e];
            int bk = d >> BKT_SHIFT;
            int rk = atomicAdd(&h[bk], 1);
            perm_tmp[base[bk] + rk] =
                (unsigned)src[e] | ((unsigned)et[e] << 17) | ((unsigned)(d & (BKT_NODES - 1)) << 20);
        }
    }
}

// One block per bucket: exact per-dst CSR. Emits doff[] and dst-sorted perm (src|et, 20 bits).
__global__ __launch_bounds__(256) void bucket_csr(const unsigned* __restrict__ perm_tmp,
                                                  const int* __restrict__ bktoff,
                                                  unsigned* __restrict__ perm,
                                                  int* __restrict__ doff, int n_nodes) {
    __shared__ int h[BKT_NODES];
    __shared__ int sa[BKT_NODES], sb[BKT_NODES];
    __shared__ int lpos[BKT_NODES];
    const int t = threadIdx.x;
    const int b = blockIdx.x;
    const int beg = bktoff[b], end = bktoff[b + 1];
    if (t < BKT_NODES) h[t] = 0;
    __syncthreads();
    for (int i = beg + t; i < end; i += 256) atomicAdd(&h[perm_tmp[i] >> 20], 1);
    __syncthreads();
    int v = (t < BKT_NODES) ? h[t] : 0;
    if (t < BKT_NODES) sa[t] = v;
    __syncthreads();
    int* pin = sa;
    int* pout = sb;
    for (int d = 1; d < BKT_NODES; d <<= 1) {
        if (t < BKT_NODES) pout[t] = pin[t] + ((t >= d) ? pin[t - d] : 0);
        __syncthreads();
        int* tmp = pin; pin = pout; pout = tmp;
    }
    if (t < BKT_NODES) {
        int excl = pin[t] - v;
        lpos[t] = beg + excl;
        int dnode = b * BKT_NODES + t;
        if (dnode < n_nodes) doff[dnode] = beg + excl;
    }
    if (b == gridDim.x - 1 && t == 0) doff[n_nodes] = end;
    __syncthreads();
    for (int i = beg + t; i < end; i += 256) {
        unsigned rc = perm_tmp[i];
        int p = atomicAdd(&lpos[rc >> 20], 1);
        perm[p] = rc & 0xFFFFFu;  // src | et<<17
    }
}

// gather4: one wave per dst; 8 edges in flight per iteration.
// lane = (edge-slot g = lane>>3, col-octet s = lane&7). Each 8-lane group loads one
// full 128B hproj row via dwordx4; 3-step shfl_xor reduces across edge-slots.
__global__ __launch_bounds__(256) void gather4(const unsigned* __restrict__ perm,
                                               const int* __restrict__ doff,
                                               const unsigned short* __restrict__ hproj,
                                               const float* __restrict__ selfbuf,
                                               float* __restrict__ out, int n_nodes) {
    int gid = blockIdx.x * blockDim.x + threadIdx.x;
    int d = gid >> 6;
    if (d >= n_nodes) return;
    int lane = gid & 63;
    int g = lane >> 3;   // edge slot 0..7
    int s = lane & 7;    // col octet 0..7
    int beg = doff[d], end = doff[d + 1];
    const size_t nn = (size_t)n_nodes;

    float acc[8];
#pragma unroll
    for (int k = 0; k < 8; ++k) acc[k] = 0.f;

    for (int i = beg; i < end; i += 8) {
        int e = i + g;
        if (e < end) {
            unsigned rc = perm[e];
            const uint4 v = *(const uint4*)(hproj +
                ((size_t)(rc >> 17) * nn + (rc & 0x1FFFFu)) * DIM + s * 8);
            acc[0] += bf2f((unsigned short)(v.x & 0xFFFFu));
            acc[1] += bf2f((unsigned short)(v.x >> 16));
            acc[2] += bf2f((unsigned short)(v.y & 0xFFFFu));
            acc[3] += bf2f((unsigned short)(v.y >> 16));
            acc[4] += bf2f((unsigned short)(v.z & 0xFFFFu));
            acc[5] += bf2f((unsigned short)(v.z >> 16));
            acc[6] += bf2f((unsigned short)(v.w & 0xFFFFu));
            acc[7] += bf2f((unsigned short)(v.w >> 16));
        }
    }
    // reduce across the 8 edge slots (lanes with equal s)
#pragma unroll
    for (int k = 0; k < 8; ++k) {
        acc[k] += __shfl_xor(acc[k], 8);
        acc[k] += __shfl_xor(acc[k], 16);
        acc[k] += __shfl_xor(acc[k], 32);
    }
    if (g == 0) {
        const float4* sb = (const float4*)(selfbuf + (size_t)d * DIM + s * 8);
        float4 o0 = sb[0], o1 = sb[1];
        o0.x += acc[0]; o0.y += acc[1]; o0.z += acc[2]; o0.w += acc[3];
        o1.x += acc[4]; o1.y += acc[5]; o1.z += acc[6]; o1.w += acc[7];
        float4* op = (float4*)(out + (size_t)d * DIM + s * 8);
        op[0] = o0;
        op[1] = o1;
    }
}

extern "C" void kernel_launch(void* const* d_in, const int* in_sizes, int n_in,
                              void* d_out, int out_size, void* d_ws, size_t ws_size,
                              hipStream_t stream) {
    const int* src = (const int*)d_in[0];
    const int* dst = (const int*)d_in[1];
    const int* et  = (const int*)d_in[2];
    const float* emb    = (const float*)d_in[3];
    const float* bases1 = (const float*)d_in[4];
    const float* coef1  = (const float*)d_in[5];
    const float* wself1 = (const float*)d_in[6];
    const float* bias1  = (const float*)d_in[7];
    const float* bases2 = (const float*)d_in[8];
    const float* coef2  = (const float*)d_in[9];
    const float* wself2 = (const float*)d_in[10];
    const float* bias2  = (const float*)d_in[11];
    float* out = (float*)d_out;

    const int NE = in_sizes[0];
    const int NN = in_sizes[3] / DIM;
    const int NBKT = (NN + BKT_NODES - 1) / BKT_NODES;  // 782

    // Workspace: Wpk1|Wpk2|selfbuf|h1|hproj|bktcnt|bktoff|bktpos|doff|perm_tmp|perm  (~164 MB)
    unsigned short* Wpk1 = (unsigned short*)d_ws;
    unsigned short* Wpk2 = Wpk1 + (size_t)NW * DIM * DIM;
    float* selfbuf = (float*)(Wpk2 + (size_t)NW * DIM * DIM);
    float* h1 = selfbuf + (size_t)NN * DIM;
    unsigned short* hproj = (unsigned short*)(h1 + (size_t)NN * DIM);
    int* bktcnt = (int*)(hproj + (size_t)NRELS * NN * DIM);
    int* bktoff = bktcnt + MAXBKT;
    int* bktpos = bktoff + MAXBKT + 1;
    int* doff = bktpos + MAXBKT;
    unsigned* perm_tmp = (unsigned*)(doff + NN + 64);
    unsigned* perm = perm_tmp + NE;

    const int wpk_threads = NW * DIM * DIM;
    build_wpk<<<(wpk_threads + 255) / 256, 256, 0, stream>>>(bases1, coef1, wself1, Wpk1);
    build_wpk<<<(wpk_threads + 255) / 256, 256, 0, stream>>>(bases2, coef2, wself2, Wpk2);

    hipMemsetAsync(bktcnt, 0, (size_t)NBKT * 4, stream);
    bucket_count<<<(NE + P1_CHUNK - 1) / P1_CHUNK, 256, 0, stream>>>(dst, bktcnt, NE, NBKT);
    scan_bkt<<<1, 1024, 0, stream>>>(bktcnt, bktoff, bktpos, NBKT);
    partition<<<(NE + P3_CHUNK - 1) / P3_CHUNK, 256, 0, stream>>>(src, dst, et, bktpos, perm_tmp, NE, NBKT);
    bucket_csr<<<NBKT, 256, 0, stream>>>(perm_tmp, bktoff, perm, doff, NN);

    const int proj_blocks = (NN + 63) / 64;
    const int gath_blocks = (NN + 3) / 4;  // one wave per dst

    // Layer 1
    proj_kernel<<<proj_blocks, 256, 0, stream>>>(emb, Wpk1, bias1, hproj, selfbuf, NN);
    gather4<<<gath_blocks, 256, 0, stream>>>(perm, doff, hproj, selfbuf, h1, NN);

    // Layer 2
    proj_kernel<<<proj_blocks, 256, 0, stream>>>(h1, Wpk2, bias2, hproj, selfbuf, NN);
    gather4<<<gath_blocks, 256, 0, stream>>>(perm, doff, hproj, selfbuf, out, NN);
}

// Round 8
// 216.638 us; speedup vs baseline: 5.3681x; 1.0380x over previous
//
#include <hip/hip_runtime.h>
#include <hip/hip_bf16.h>

#define DIM 64
#define NRELS 8
#define NBASES 4
#define NW 9              // 8 relations + self
#define BKT_SHIFT 7
#define BKT_NODES 128     // nodes per bucket
#define MAXBKT 1024
#define P1_CHUNK 2048
#define P3_CHUNK 4096

typedef __attribute__((ext_vector_type(8))) short short8;
typedef __attribute__((ext_vector_type(4))) float f32x4;

__device__ inline unsigned short f2bf(float f) {
    union { float f; unsigned int u; } v; v.f = f;
    unsigned int u = v.u;
    unsigned int r = u + 0x7FFFu + ((u >> 16) & 1u);  // round-to-nearest-even
    return (unsigned short)(r >> 16);
}
__device__ inline float bf2f(unsigned short s) {
    union { unsigned int u; float f; } v; v.u = ((unsigned int)s) << 16;
    return v.f;
}

// Pack BOTH layers' W matrices (8 relation + 1 self each) into MFMA B-fragment order, bf16.
// B element for mfma_f32_16x16x32_bf16: k = half*32 + (lane>>4)*8 + e, j = jt*16 + (lane&15)
__global__ void build_wpk2(const float* __restrict__ bases1, const float* __restrict__ coef1,
                           const float* __restrict__ wself1, unsigned short* __restrict__ Wpk1,
                           const float* __restrict__ bases2, const float* __restrict__ coef2,
                           const float* __restrict__ wself2, unsigned short* __restrict__ Wpk2) {
    int idx = blockIdx.x * blockDim.x + threadIdx.x;
    if (idx >= 2 * NW * DIM * DIM) return;
    int set = (idx >= NW * DIM * DIM);
    const float* bases = set ? bases2 : bases1;
    const float* coef  = set ? coef2 : coef1;
    const float* wself = set ? wself2 : wself1;
    unsigned short* Wpk = set ? Wpk2 : Wpk1;
    idx -= set * NW * DIM * DIM;
    int r = idx >> 12;
    int k = (idx >> 6) & 63;
    int j = idx & 63;
    float v;
    if (r < NRELS) {
        v = 0.f;
#pragma unroll
        for (int b = 0; b < NBASES; ++b)
            v += coef[r * NBASES + b] * bases[((size_t)b * DIM + k) * DIM + j];
    } else {
        v = wself[k * DIM + j];
    }
    int half = k >> 5, e = k & 7, laneHi = (k >> 3) & 3;
    int jt = j >> 4, laneLo = j & 15;
    int lane = laneHi * 16 + laneLo;
    Wpk[(size_t)((((r * 4 + jt) * 2 + half) * 64 + lane) * 8 + e)] = f2bf(v);
}

// Per 64-node tile (4 waves x 16 nodes):
//   hproj[r][n][:] = bf16( h[n] @ W_r ),  selfbuf[n][:] = h[n] @ wself + bias (f32)
__global__ __launch_bounds__(256) void proj_kernel(const float* __restrict__ h,
                                                   const unsigned short* __restrict__ Wpk,
                                                   const float* __restrict__ bias,
                                                   unsigned short* __restrict__ hproj,
                                                   float* __restrict__ selfbuf, int n_nodes) {
    const int lane = threadIdx.x & 63;
    const int wave = threadIdx.x >> 6;
    const int n0 = blockIdx.x * 64 + wave * 16;
    __shared__ unsigned short tile[4][16][64];  // 8 KB; per-wave private slice
    if (n0 >= n_nodes) return;
    const int lrow = lane & 15;
    const int lhi = lane >> 4;

    int row = n0 + lrow;
    if (row >= n_nodes) row = n_nodes - 1;
    const float* hrow = h + (size_t)row * DIM + lhi * 8;
    float4 x0 = *(const float4*)(hrow);
    float4 x1 = *(const float4*)(hrow + 4);
    float4 x2 = *(const float4*)(hrow + 32);
    float4 x3 = *(const float4*)(hrow + 36);
    short8 a0, a1;
    a0[0] = (short)f2bf(x0.x); a0[1] = (short)f2bf(x0.y);
    a0[2] = (short)f2bf(x0.z); a0[3] = (short)f2bf(x0.w);
    a0[4] = (short)f2bf(x1.x); a0[5] = (short)f2bf(x1.y);
    a0[6] = (short)f2bf(x1.z); a0[7] = (short)f2bf(x1.w);
    a1[0] = (short)f2bf(x2.x); a1[1] = (short)f2bf(x2.y);
    a1[2] = (short)f2bf(x2.z); a1[3] = (short)f2bf(x2.w);
    a1[4] = (short)f2bf(x3.x); a1[5] = (short)f2bf(x3.y);
    a1[6] = (short)f2bf(x3.z); a1[7] = (short)f2bf(x3.w);

    unsigned short (*T)[64] = tile[wave];
    const int rrow = lane >> 2, seg = lane & 3;

    for (int r = 0; r < NW; ++r) {
        f32x4 c[4];
#pragma unroll
        for (int jt = 0; jt < 4; ++jt) {
            const unsigned short* bbase = Wpk + (size_t)(((r * 4 + jt) * 2) * 64 + lane) * 8;
            short8 b0 = *(const short8*)bbase;
            short8 b1 = *(const short8*)(bbase + 512);
            f32x4 cc = {0.f, 0.f, 0.f, 0.f};
            cc = __builtin_amdgcn_mfma_f32_16x16x32_bf16(a0, b0, cc, 0, 0, 0);
            cc = __builtin_amdgcn_mfma_f32_16x16x32_bf16(a1, b1, cc, 0, 0, 0);
            c[jt] = cc;
        }
        if (r < NRELS) {
#pragma unroll
            for (int jt = 0; jt < 4; ++jt)
#pragma unroll
                for (int reg = 0; reg < 4; ++reg)
                    T[lhi * 4 + reg][jt * 16 + lrow] = f2bf(c[jt][reg]);
            float4 lo = *(const float4*)&T[rrow][seg * 16];
            float4 hi = *(const float4*)&T[rrow][seg * 16 + 8];
            if (n0 + rrow < n_nodes) {
                float4* dp = (float4*)(hproj + ((size_t)r * n_nodes + n0 + rrow) * DIM + seg * 16);
                dp[0] = lo;
                dp[1] = hi;
            }
        } else {
#pragma unroll
            for (int jt = 0; jt < 4; ++jt) {
                int j = jt * 16 + lrow;
                float bj = bias[j];
                float* op = selfbuf + (size_t)n0 * DIM + j;
#pragma unroll
                for (int reg = 0; reg < 4; ++reg) {
                    int i = lhi * 4 + reg;
                    if (n0 + i < n_nodes) op[(size_t)i * DIM] = c[jt][reg] + bj;
                }
            }
        }
    }
}

// ---- two-level CSR build ----

__global__ __launch_bounds__(256) void bucket_count(const int* __restrict__ dst,
                                                    int* __restrict__ bktcnt,
                                                    int n_edges, int nbkt) {
    __shared__ int h[MAXBKT];
    int t = threadIdx.x;
    for (int i = t; i < nbkt; i += 256) h[i] = 0;
    __syncthreads();
    int e0 = blockIdx.x * P1_CHUNK;
#pragma unroll
    for (int k = 0; k < P1_CHUNK / 256; ++k) {
        int e = e0 + k * 256 + t;
        if (e < n_edges) atomicAdd(&h[dst[e] >> BKT_SHIFT], 1);
    }
    __syncthreads();
    for (int i = t; i < nbkt; i += 256)
        if (h[i]) atomicAdd(&bktcnt[i], h[i]);
}

__global__ __launch_bounds__(1024) void scan_bkt(const int* __restrict__ cnt,
                                                 int* __restrict__ off,
                                                 int* __restrict__ pos, int nbkt) {
    __shared__ int a[1024], b[1024];
    int t = threadIdx.x;
    int v = (t < nbkt) ? cnt[t] : 0;
    a[t] = v;
    __syncthreads();
    int* pin = a;
    int* pout = b;
    for (int d = 1; d < 1024; d <<= 1) {
        pout[t] = pin[t] + ((t >= d) ? pin[t - d] : 0);
        __syncthreads();
        int* tmp = pin; pin = pout; pout = tmp;
    }
    int incl = pin[t];
    int excl = incl - v;
    if (t < nbkt) { off[t] = excl; pos[t] = excl; }
    if (t == 1023) off[nbkt] = incl;
}

// Partition edges into bucket-contiguous perm_tmp, packed src | et<<17 | dstlow<<20
__global__ __launch_bounds__(256) void partition(const int* __restrict__ src,
                                                 const int* __restrict__ dst,
                                                 const int* __restrict__ et,
                                                 int* __restrict__ bktpos,
                                                 unsigned* __restrict__ perm_tmp,
                                                 int n_edges, int nbkt) {
    __shared__ int h[MAXBKT];
    __shared__ int base[MAXBKT];
    int t = threadIdx.x;
    for (int i = t; i < nbkt; i += 256) h[i] = 0;
    __syncthreads();
    int e0 = blockIdx.x * P3_CHUNK;
#pragma unroll
    for (int k = 0; k < P3_CHUNK / 256; ++k) {
        int e = e0 + k * 256 + t;
        if (e < n_edges) atomicAdd(&h[dst[e] >> BKT_SHIFT], 1);
    }
    __syncthreads();
    for (int i = t; i < nbkt; i += 256) {
        int c = h[i];
        base[i] = c ? atomicAdd(&bktpos[i], c) : 0;
        h[i] = 0;
    }
    __syncthreads();
#pragma unroll
    for (int k = 0; k < P3_CHUNK / 256; ++k) {
        int e = e0 + k * 256 + t;
        if (e < n_edges) {
            int d = dst[e];
            int bk = d >> BKT_SHIFT;
            int rk = atomicAdd(&h[bk], 1);
            perm_tmp[base[bk] + rk] =
                (unsigned)src[e] | ((unsigned)et[e] << 17) | ((unsigned)(d & (BKT_NODES - 1)) << 20);
        }
    }
}

// One block per bucket: exact per-dst CSR. Emits doff[] and dst-sorted perm (src|et, 20 bits).
__global__ __launch_bounds__(256) void bucket_csr(const unsigned* __restrict__ perm_tmp,
                                                  const int* __restrict__ bktoff,
                                                  unsigned* __restrict__ perm,
                                                  int* __restrict__ doff, int n_nodes) {
    __shared__ int h[BKT_NODES];
    __shared__ int sa[BKT_NODES], sb[BKT_NODES];
    __shared__ int lpos[BKT_NODES];
    const int t = threadIdx.x;
    const int b = blockIdx.x;
    const int beg = bktoff[b], end = bktoff[b + 1];
    if (t < BKT_NODES) h[t] = 0;
    __syncthreads();
    for (int i = beg + t; i < end; i += 256) atomicAdd(&h[perm_tmp[i] >> 20], 1);
    __syncthreads();
    int v = (t < BKT_NODES) ? h[t] : 0;
    if (t < BKT_NODES) sa[t] = v;
    __syncthreads();
    int* pin = sa;
    int* pout = sb;
    for (int d = 1; d < BKT_NODES; d <<= 1) {
        if (t < BKT_NODES) pout[t] = pin[t] + ((t >= d) ? pin[t - d] : 0);
        __syncthreads();
        int* tmp = pin; pin = pout; pout = tmp;
    }
    if (t < BKT_NODES) {
        int excl = pin[t] - v;
        lpos[t] = beg + excl;
        int dnode = b * BKT_NODES + t;
        if (dnode < n_nodes) doff[dnode] = beg + excl;
    }
    if (b == gridDim.x - 1 && t == 0) doff[n_nodes] = end;
    __syncthreads();
    for (int i = beg + t; i < end; i += 256) {
        unsigned rc = perm_tmp[i];
        int p = atomicAdd(&lpos[rc >> 20], 1);
        perm[p] = rc & 0xFFFFFu;  // src | et<<17
    }
}

// gather5: one wave per dst; 16 edges in flight per iteration (two 8-slot sets
// double-issued). lane = (edge-slot g = lane>>3, col-octet s = lane&7); each
// 8-lane group loads one full 128B hproj row via dwordx4.
__global__ __launch_bounds__(256) void gather5(const unsigned* __restrict__ perm,
                                               const int* __restrict__ doff,
                                               const unsigned short* __restrict__ hproj,
                                               const float* __restrict__ selfbuf,
                                               float* __restrict__ out, int n_nodes) {
    int gid = blockIdx.x * blockDim.x + threadIdx.x;
    int d = gid >> 6;
    if (d >= n_nodes) return;
    int lane = gid & 63;
    int g = lane >> 3;   // edge slot 0..7
    int s = lane & 7;    // col octet 0..7
    int beg = doff[d], end = doff[d + 1];
    const size_t nn = (size_t)n_nodes;

    float acc[8];
#pragma unroll
    for (int k = 0; k < 8; ++k) acc[k] = 0.f;

    for (int i = beg; i < end; i += 16) {
        int eA = i + g;
        int eB = i + 8 + g;
        bool va = eA < end, vb = eB < end;
        unsigned rcA = va ? perm[eA] : 0u;
        unsigned rcB = vb ? perm[eB] : 0u;
        uint4 vA = make_uint4(0u, 0u, 0u, 0u);
        uint4 vB = make_uint4(0u, 0u, 0u, 0u);
        if (va) vA = *(const uint4*)(hproj + ((size_t)(rcA >> 17) * nn + (rcA & 0x1FFFFu)) * DIM + s * 8);
        if (vb) vB = *(const uint4*)(hproj + ((size_t)(rcB >> 17) * nn + (rcB & 0x1FFFFu)) * DIM + s * 8);
        acc[0] += bf2f((unsigned short)(vA.x & 0xFFFFu));
        acc[1] += bf2f((unsigned short)(vA.x >> 16));
        acc[2] += bf2f((unsigned short)(vA.y & 0xFFFFu));
        acc[3] += bf2f((unsigned short)(vA.y >> 16));
        acc[4] += bf2f((unsigned short)(vA.z & 0xFFFFu));
        acc[5] += bf2f((unsigned short)(vA.z >> 16));
        acc[6] += bf2f((unsigned short)(vA.w & 0xFFFFu));
        acc[7] += bf2f((unsigned short)(vA.w >> 16));
        acc[0] += bf2f((unsigned short)(vB.x & 0xFFFFu));
        acc[1] += bf2f((unsigned short)(vB.x >> 16));
        acc[2] += bf2f((unsigned short)(vB.y & 0xFFFFu));
        acc[3] += bf2f((unsigned short)(vB.y >> 16));
        acc[4] += bf2f((unsigned short)(vB.z & 0xFFFFu));
        acc[5] += bf2f((unsigned short)(vB.z >> 16));
        acc[6] += bf2f((unsigned short)(vB.w & 0xFFFFu));
        acc[7] += bf2f((unsigned short)(vB.w >> 16));
    }
    // reduce across the 8 edge slots (lanes with equal s)
#pragma unroll
    for (int k = 0; k < 8; ++k) {
        acc[k] += __shfl_xor(acc[k], 8);
        acc[k] += __shfl_xor(acc[k], 16);
        acc[k] += __shfl_xor(acc[k], 32);
    }
    if (g == 0) {
        const float4* sb = (const float4*)(selfbuf + (size_t)d * DIM + s * 8);
        float4 o0 = sb[0], o1 = sb[1];
        o0.x += acc[0]; o0.y += acc[1]; o0.z += acc[2]; o0.w += acc[3];
        o1.x += acc[4]; o1.y += acc[5]; o1.z += acc[6]; o1.w += acc[7];
        float4* op = (float4*)(out + (size_t)d * DIM + s * 8);
        op[0] = o0;
        op[1] = o1;
    }
}

extern "C" void kernel_launch(void* const* d_in, const int* in_sizes, int n_in,
                              void* d_out, int out_size, void* d_ws, size_t ws_size,
                              hipStream_t stream) {
    const int* src = (const int*)d_in[0];
    const int* dst = (const int*)d_in[1];
    const int* et  = (const int*)d_in[2];
    const float* emb    = (const float*)d_in[3];
    const float* bases1 = (const float*)d_in[4];
    const float* coef1  = (const float*)d_in[5];
    const float* wself1 = (const float*)d_in[6];
    const float* bias1  = (const float*)d_in[7];
    const float* bases2 = (const float*)d_in[8];
    const float* coef2  = (const float*)d_in[9];
    const float* wself2 = (const float*)d_in[10];
    const float* bias2  = (const float*)d_in[11];
    float* out = (float*)d_out;

    const int NE = in_sizes[0];
    const int NN = in_sizes[3] / DIM;
    const int NBKT = (NN + BKT_NODES - 1) / BKT_NODES;  // 782

    // Workspace: Wpk1|Wpk2|selfbuf|h1|hproj|bktcnt|bktoff|bktpos|doff|perm_tmp|perm  (~164 MB)
    unsigned short* Wpk1 = (unsigned short*)d_ws;
    unsigned short* Wpk2 = Wpk1 + (size_t)NW * DIM * DIM;
    float* selfbuf = (float*)(Wpk2 + (size_t)NW * DIM * DIM);
    float* h1 = selfbuf + (size_t)NN * DIM;
    unsigned short* hproj = (unsigned short*)(h1 + (size_t)NN * DIM);
    int* bktcnt = (int*)(hproj + (size_t)NRELS * NN * DIM);
    int* bktoff = bktcnt + MAXBKT;
    int* bktpos = bktoff + MAXBKT + 1;
    int* doff = bktpos + MAXBKT;
    unsigned* perm_tmp = (unsigned*)(doff + NN + 64);
    unsigned* perm = perm_tmp + NE;

    const int wpk_threads = 2 * NW * DIM * DIM;
    build_wpk2<<<(wpk_threads + 255) / 256, 256, 0, stream>>>(bases1, coef1, wself1, Wpk1,
                                                              bases2, coef2, wself2, Wpk2);

    hipMemsetAsync(bktcnt, 0, (size_t)NBKT * 4, stream);
    bucket_count<<<(NE + P1_CHUNK - 1) / P1_CHUNK, 256, 0, stream>>>(dst, bktcnt, NE, NBKT);
    scan_bkt<<<1, 1024, 0, stream>>>(bktcnt, bktoff, bktpos, NBKT);
    partition<<<(NE + P3_CHUNK - 1) / P3_CHUNK, 256, 0, stream>>>(src, dst, et, bktpos, perm_tmp, NE, NBKT);
    bucket_csr<<<NBKT, 256, 0, stream>>>(perm_tmp, bktoff, perm, doff, NN);

    const int proj_blocks = (NN + 63) / 64;
    const int gath_blocks = (NN + 3) / 4;  // one wave per dst

    // Layer 1
    proj_kernel<<<proj_blocks, 256, 0, stream>>>(emb, Wpk1, bias1, hproj, selfbuf, NN);
    gather5<<<gath_blocks, 256, 0, stream>>>(perm, doff, hproj, selfbuf, h1, NN);

    // Layer 2
    proj_kernel<<<proj_blocks, 256, 0, stream>>>(h1, Wpk2, bias2, hproj, selfbuf, NN);
    gather5<<<gath_blocks, 256, 0, stream>>>(perm, doff, hproj, selfbuf, out, NN);
}

// Round 9
// 215.680 us; speedup vs baseline: 5.3919x; 1.0044x over previous
//
#include <hip/hip_runtime.h>
#include <hip/hip_bf16.h>

#define DIM 64
#define NRELS 8
#define NBASES 4
#define NW 9              // 8 relations + self
#define BKT_SHIFT 7
#define BKT_NODES 128     // nodes per bucket
#define MAXBKT 1024
#define P1_CHUNK 2048
#define P3_CHUNK 4096

typedef __attribute__((ext_vector_type(8))) short short8;
typedef __attribute__((ext_vector_type(4))) float f32x4;

__device__ inline unsigned short f2bf(float f) {
    union { float f; unsigned int u; } v; v.f = f;
    unsigned int u = v.u;
    unsigned int r = u + 0x7FFFu + ((u >> 16) & 1u);  // round-to-nearest-even
    return (unsigned short)(r >> 16);
}
__device__ inline float bf2f(unsigned short s) {
    union { unsigned int u; float f; } v; v.u = ((unsigned int)s) << 16;
    return v.f;
}

// Pack BOTH layers' W matrices (8 relation + 1 self each) into MFMA B-fragment order, bf16.
// B element for mfma_f32_16x16x32_bf16: k = half*32 + (lane>>4)*8 + e, j = jt*16 + (lane&15)
__global__ void build_wpk2(const float* __restrict__ bases1, const float* __restrict__ coef1,
                           const float* __restrict__ wself1, unsigned short* __restrict__ Wpk1,
                           const float* __restrict__ bases2, const float* __restrict__ coef2,
                           const float* __restrict__ wself2, unsigned short* __restrict__ Wpk2) {
    int idx = blockIdx.x * blockDim.x + threadIdx.x;
    if (idx >= 2 * NW * DIM * DIM) return;
    int set = (idx >= NW * DIM * DIM);
    const float* bases = set ? bases2 : bases1;
    const float* coef  = set ? coef2 : coef1;
    const float* wself = set ? wself2 : wself1;
    unsigned short* Wpk = set ? Wpk2 : Wpk1;
    idx -= set * NW * DIM * DIM;
    int r = idx >> 12;
    int k = (idx >> 6) & 63;
    int j = idx & 63;
    float v;
    if (r < NRELS) {
        v = 0.f;
#pragma unroll
        for (int b = 0; b < NBASES; ++b)
            v += coef[r * NBASES + b] * bases[((size_t)b * DIM + k) * DIM + j];
    } else {
        v = wself[k * DIM + j];
    }
    int half = k >> 5, e = k & 7, laneHi = (k >> 3) & 3;
    int jt = j >> 4, laneLo = j & 15;
    int lane = laneHi * 16 + laneLo;
    Wpk[(size_t)((((r * 4 + jt) * 2 + half) * 64 + lane) * 8 + e)] = f2bf(v);
}

// Per 64-node tile (4 waves x 16 nodes), NO LDS:
//   hproj rows stored in fragment-permuted order: position p = c*4 + jt  <->  col jt*16+c.
//   Each lane stores dwordx2 per row (4 insts/relation, 4x128B fully-covered lines).
//   selfbuf[n][:] = h[n] @ wself + bias (f32, TRUE column order).
__global__ __launch_bounds__(256) void proj_kernel(const float* __restrict__ h,
                                                   const unsigned short* __restrict__ Wpk,
                                                   const float* __restrict__ bias,
                                                   unsigned short* __restrict__ hproj,
                                                   float* __restrict__ selfbuf, int n_nodes) {
    const int lane = threadIdx.x & 63;
    const int wave = threadIdx.x >> 6;
    const int n0 = blockIdx.x * 64 + wave * 16;
    if (n0 >= n_nodes) return;
    const int lrow = lane & 15;  // A row within 16-tile / D col (c)
    const int lhi = lane >> 4;   // D row-group

    int row = n0 + lrow;
    if (row >= n_nodes) row = n_nodes - 1;
    const float* hrow = h + (size_t)row * DIM + lhi * 8;
    float4 x0 = *(const float4*)(hrow);
    float4 x1 = *(const float4*)(hrow + 4);
    float4 x2 = *(const float4*)(hrow + 32);
    float4 x3 = *(const float4*)(hrow + 36);
    short8 a0, a1;
    a0[0] = (short)f2bf(x0.x); a0[1] = (short)f2bf(x0.y);
    a0[2] = (short)f2bf(x0.z); a0[3] = (short)f2bf(x0.w);
    a0[4] = (short)f2bf(x1.x); a0[5] = (short)f2bf(x1.y);
    a0[6] = (short)f2bf(x1.z); a0[7] = (short)f2bf(x1.w);
    a1[0] = (short)f2bf(x2.x); a1[1] = (short)f2bf(x2.y);
    a1[2] = (short)f2bf(x2.z); a1[3] = (short)f2bf(x2.w);
    a1[4] = (short)f2bf(x3.x); a1[5] = (short)f2bf(x3.y);
    a1[6] = (short)f2bf(x3.z); a1[7] = (short)f2bf(x3.w);

    const size_t nn = (size_t)n_nodes;

    for (int r = 0; r < NW; ++r) {
        f32x4 c[4];
#pragma unroll
        for (int jt = 0; jt < 4; ++jt) {
            const unsigned short* bbase = Wpk + (size_t)(((r * 4 + jt) * 2) * 64 + lane) * 8;
            short8 b0 = *(const short8*)bbase;
            short8 b1 = *(const short8*)(bbase + 512);
            f32x4 cc = {0.f, 0.f, 0.f, 0.f};
            cc = __builtin_amdgcn_mfma_f32_16x16x32_bf16(a0, b0, cc, 0, 0, 0);
            cc = __builtin_amdgcn_mfma_f32_16x16x32_bf16(a1, b1, cc, 0, 0, 0);
            c[jt] = cc;
        }
        if (r < NRELS) {
            // permuted row store: node = n0 + lhi*4 + reg; 8B at ushort offset lrow*4
            unsigned short* rb = hproj + ((size_t)r * nn + (size_t)(n0 + lhi * 4)) * DIM + lrow * 4;
#pragma unroll
            for (int reg = 0; reg < 4; ++reg) {
                if (n0 + lhi * 4 + reg < n_nodes) {
                    unsigned lo = (unsigned)f2bf(c[0][reg]) | ((unsigned)f2bf(c[1][reg]) << 16);
                    unsigned hi = (unsigned)f2bf(c[2][reg]) | ((unsigned)f2bf(c[3][reg]) << 16);
                    uint2 v; v.x = lo; v.y = hi;
                    *(uint2*)(rb + (size_t)reg * DIM) = v;
                }
            }
        } else {
#pragma unroll
            for (int jt = 0; jt < 4; ++jt) {
                int j = jt * 16 + lrow;
                float bj = bias[j];
                float* op = selfbuf + (size_t)n0 * DIM + j;
#pragma unroll
                for (int reg = 0; reg < 4; ++reg) {
                    int i = lhi * 4 + reg;
                    if (n0 + i < n_nodes) op[(size_t)i * DIM] = c[jt][reg] + bj;
                }
            }
        }
    }
}

// ---- two-level CSR build ----

__global__ __launch_bounds__(256) void bucket_count(const int* __restrict__ dst,
                                                    int* __restrict__ bktcnt,
                                                    int n_edges, int nbkt) {
    __shared__ int h[MAXBKT];
    int t = threadIdx.x;
    for (int i = t; i < nbkt; i += 256) h[i] = 0;
    __syncthreads();
    int e0 = blockIdx.x * P1_CHUNK;
#pragma unroll
    for (int k = 0; k < P1_CHUNK / 256; ++k) {
        int e = e0 + k * 256 + t;
        if (e < n_edges) atomicAdd(&h[dst[e] >> BKT_SHIFT], 1);
    }
    __syncthreads();
    for (int i = t; i < nbkt; i += 256)
        if (h[i]) atomicAdd(&bktcnt[i], h[i]);
}

__global__ __launch_bounds__(1024) void scan_bkt(const int* __restrict__ cnt,
                                                 int* __restrict__ off,
                                                 int* __restrict__ pos, int nbkt) {
    __shared__ int a[1024], b[1024];
    int t = threadIdx.x;
    int v = (t < nbkt) ? cnt[t] : 0;
    a[t] = v;
    __syncthreads();
    int* pin = a;
    int* pout = b;
    for (int d = 1; d < 1024; d <<= 1) {
        pout[t] = pin[t] + ((t >= d) ? pin[t - d] : 0);
        __syncthreads();
        int* tmp = pin; pin = pout; pout = tmp;
    }
    int incl = pin[t];
    int excl = incl - v;
    if (t < nbkt) { off[t] = excl; pos[t] = excl; }
    if (t == 1023) off[nbkt] = incl;
}

// Partition edges into bucket-contiguous perm_tmp, packed src | et<<17 | dstlow<<20
__global__ __launch_bounds__(256) void partition(const int* __restrict__ src,
                                                 const int* __restrict__ dst,
                                                 const int* __restrict__ et,
                                                 int* __restrict__ bktpos,
                                                 unsigned* __restrict__ perm_tmp,
                                                 int n_edges, int nbkt) {
    __shared__ int h[MAXBKT];
    __shared__ int base[MAXBKT];
    int t = threadIdx.x;
    for (int i = t; i < nbkt; i += 256) h[i] = 0;
    __syncthreads();
    int e0 = blockIdx.x * P3_CHUNK;
#pragma unroll
    for (int k = 0; k < P3_CHUNK / 256; ++k) {
        int e = e0 + k * 256 + t;
        if (e < n_edges) atomicAdd(&h[dst[e] >> BKT_SHIFT], 1);
    }
    __syncthreads();
    for (int i = t; i < nbkt; i += 256) {
        int c = h[i];
        base[i] = c ? atomicAdd(&bktpos[i], c) : 0;
        h[i] = 0;
    }
    __syncthreads();
#pragma unroll
    for (int k = 0; k < P3_CHUNK / 256; ++k) {
        int e = e0 + k * 256 + t;
        if (e < n_edges) {
            int d = dst[e];
            int bk = d >> BKT_SHIFT;
            int rk = atomicAdd(&h[bk], 1);
            perm_tmp[base[bk] + rk] =
                (unsigned)src[e] | ((unsigned)et[e] << 17) | ((unsigned)(d & (BKT_NODES - 1)) << 20);
        }
    }
}

// One block per bucket: exact per-dst CSR. Emits doff[] and dst-sorted perm (src|et, 20 bits).
__global__ __launch_bounds__(256) void bucket_csr(const unsigned* __restrict__ perm_tmp,
                                                  const int* __restrict__ bktoff,
                                                  unsigned* __restrict__ perm,
                                                  int* __restrict__ doff, int n_nodes) {
    __shared__ int h[BKT_NODES];
    __shared__ int sa[BKT_NODES], sb[BKT_NODES];
    __shared__ int lpos[BKT_NODES];
    const int t = threadIdx.x;
    const int b = blockIdx.x;
    const int beg = bktoff[b], end = bktoff[b + 1];
    if (t < BKT_NODES) h[t] = 0;
    __syncthreads();
    for (int i = beg + t; i < end; i += 256) atomicAdd(&h[perm_tmp[i] >> 20], 1);
    __syncthreads();
    int v = (t < BKT_NODES) ? h[t] : 0;
    if (t < BKT_NODES) sa[t] = v;
    __syncthreads();
    int* pin = sa;
    int* pout = sb;
    for (int d = 1; d < BKT_NODES; d <<= 1) {
        if (t < BKT_NODES) pout[t] = pin[t] + ((t >= d) ? pin[t - d] : 0);
        __syncthreads();
        int* tmp = pin; pin = pout; pout = tmp;
    }
    if (t < BKT_NODES) {
        int excl = pin[t] - v;
        lpos[t] = beg + excl;
        int dnode = b * BKT_NODES + t;
        if (dnode < n_nodes) doff[dnode] = beg + excl;
    }
    if (b == gridDim.x - 1 && t == 0) doff[n_nodes] = end;
    __syncthreads();
    for (int i = beg + t; i < end; i += 256) {
        unsigned rc = perm_tmp[i];
        int p = atomicAdd(&lpos[rc >> 20], 1);
        perm[p] = rc & 0xFFFFFu;  // src | et<<17
    }
}

// gather6: one wave per dst; 16 edges in flight per iteration. Reads fragment-permuted
// hproj rows (position p = c*4 + jt <-> col jt*16+c); epilogue unpermutes with
// float2 stores at cols (jt*16 + 2s, jt*16 + 2s + 1).
__global__ __launch_bounds__(256) void gather6(const unsigned* __restrict__ perm,
                                               const int* __restrict__ doff,
                                               const unsigned short* __restrict__ hproj,
                                               const float* __restrict__ selfbuf,
                                               float* __restrict__ out, int n_nodes) {
    int gid = blockIdx.x * blockDim.x + threadIdx.x;
    int d = gid >> 6;
    if (d >= n_nodes) return;
    int lane = gid & 63;
    int g = lane >> 3;   // edge slot 0..7
    int s = lane & 7;    // 16B chunk index within row
    int beg = doff[d], end = doff[d + 1];
    const size_t nn = (size_t)n_nodes;

    float acc[8];
#pragma unroll
    for (int k = 0; k < 8; ++k) acc[k] = 0.f;

    for (int i = beg; i < end; i += 16) {
        int eA = i + g;
        int eB = i + 8 + g;
        bool va = eA < end, vb = eB < end;
        unsigned rcA = va ? perm[eA] : 0u;
        unsigned rcB = vb ? perm[eB] : 0u;
        uint4 vA = make_uint4(0u, 0u, 0u, 0u);
        uint4 vB = make_uint4(0u, 0u, 0u, 0u);
        if (va) vA = *(const uint4*)(hproj + ((size_t)(rcA >> 17) * nn + (rcA & 0x1FFFFu)) * DIM + s * 8);
        if (vb) vB = *(const uint4*)(hproj + ((size_t)(rcB >> 17) * nn + (rcB & 0x1FFFFu)) * DIM + s * 8);
        acc[0] += bf2f((unsigned short)(vA.x & 0xFFFFu));
        acc[1] += bf2f((unsigned short)(vA.x >> 16));
        acc[2] += bf2f((unsigned short)(vA.y & 0xFFFFu));
        acc[3] += bf2f((unsigned short)(vA.y >> 16));
        acc[4] += bf2f((unsigned short)(vA.z & 0xFFFFu));
        acc[5] += bf2f((unsigned short)(vA.z >> 16));
        acc[6] += bf2f((unsigned short)(vA.w & 0xFFFFu));
        acc[7] += bf2f((unsigned short)(vA.w >> 16));
        acc[0] += bf2f((unsigned short)(vB.x & 0xFFFFu));
        acc[1] += bf2f((unsigned short)(vB.x >> 16));
        acc[2] += bf2f((unsigned short)(vB.y & 0xFFFFu));
        acc[3] += bf2f((unsigned short)(vB.y >> 16));
        acc[4] += bf2f((unsigned short)(vB.z & 0xFFFFu));
        acc[5] += bf2f((unsigned short)(vB.z >> 16));
        acc[6] += bf2f((unsigned short)(vB.w & 0xFFFFu));
        acc[7] += bf2f((unsigned short)(vB.w >> 16));
    }
    // reduce across the 8 edge slots (lanes with equal s)
#pragma unroll
    for (int k = 0; k < 8; ++k) {
        acc[k] += __shfl_xor(acc[k], 8);
        acc[k] += __shfl_xor(acc[k], 16);
        acc[k] += __shfl_xor(acc[k], 32);
    }
    if (g == 0) {
        // acc[u] holds col (u&3)*16 + 2s + (u>>2):
        //   acc[jt] -> col jt*16+2s,  acc[4+jt] -> col jt*16+2s+1
#pragma unroll
        for (int jt = 0; jt < 4; ++jt) {
            const float2 sv = *(const float2*)(selfbuf + (size_t)d * DIM + jt * 16 + 2 * s);
            float2 o; o.x = acc[jt] + sv.x; o.y = acc[4 + jt] + sv.y;
            *(float2*)(out + (size_t)d * DIM + jt * 16 + 2 * s) = o;
        }
    }
}

extern "C" void kernel_launch(void* const* d_in, const int* in_sizes, int n_in,
                              void* d_out, int out_size, void* d_ws, size_t ws_size,
                              hipStream_t stream) {
    const int* src = (const int*)d_in[0];
    const int* dst = (const int*)d_in[1];
    const int* et  = (const int*)d_in[2];
    const float* emb    = (const float*)d_in[3];
    const float* bases1 = (const float*)d_in[4];
    const float* coef1  = (const float*)d_in[5];
    const float* wself1 = (const float*)d_in[6];
    const float* bias1  = (const float*)d_in[7];
    const float* bases2 = (const float*)d_in[8];
    const float* coef2  = (const float*)d_in[9];
    const float* wself2 = (const float*)d_in[10];
    const float* bias2  = (const float*)d_in[11];
    float* out = (float*)d_out;

    const int NE = in_sizes[0];
    const int NN = in_sizes[3] / DIM;
    const int NBKT = (NN + BKT_NODES - 1) / BKT_NODES;  // 782

    // Workspace: Wpk1|Wpk2|selfbuf|h1|hproj|bktcnt|bktoff|bktpos|doff|perm_tmp|perm  (~164 MB)
    unsigned short* Wpk1 = (unsigned short*)d_ws;
    unsigned short* Wpk2 = Wpk1 + (size_t)NW * DIM * DIM;
    float* selfbuf = (float*)(Wpk2 + (size_t)NW * DIM * DIM);
    float* h1 = selfbuf + (size_t)NN * DIM;
    unsigned short* hproj = (unsigned short*)(h1 + (size_t)NN * DIM);
    int* bktcnt = (int*)(hproj + (size_t)NRELS * NN * DIM);
    int* bktoff = bktcnt + MAXBKT;
    int* bktpos = bktoff + MAXBKT + 1;
    int* doff = bktpos + MAXBKT;
    unsigned* perm_tmp = (unsigned*)(doff + NN + 64);
    unsigned* perm = perm_tmp + NE;

    const int wpk_threads = 2 * NW * DIM * DIM;
    build_wpk2<<<(wpk_threads + 255) / 256, 256, 0, stream>>>(bases1, coef1, wself1, Wpk1,
                                                              bases2, coef2, wself2, Wpk2);

    hipMemsetAsync(bktcnt, 0, (size_t)NBKT * 4, stream);
    bucket_count<<<(NE + P1_CHUNK - 1) / P1_CHUNK, 256, 0, stream>>>(dst, bktcnt, NE, NBKT);
    scan_bkt<<<1, 1024, 0, stream>>>(bktcnt, bktoff, bktpos, NBKT);
    partition<<<(NE + P3_CHUNK - 1) / P3_CHUNK, 256, 0, stream>>>(src, dst, et, bktpos, perm_tmp, NE, NBKT);
    bucket_csr<<<NBKT, 256, 0, stream>>>(perm_tmp, bktoff, perm, doff, NN);

    const int proj_blocks = (NN + 63) / 64;
    const int gath_blocks = (NN + 3) / 4;  // one wave per dst

    // Layer 1
    proj_kernel<<<proj_blocks, 256, 0, stream>>>(emb, Wpk1, bias1, hproj, selfbuf, NN);
    gather6<<<gath_blocks, 256, 0, stream>>>(perm, doff, hproj, selfbuf, h1, NN);

    // Layer 2
    proj_kernel<<<proj_blocks, 256, 0, stream>>>(h1, Wpk2, bias2, hproj, selfbuf, NN);
    gather6<<<gath_blocks, 256, 0, stream>>>(perm, doff, hproj, selfbuf, out, NN);
}

// Round 10
// 208.773 us; speedup vs baseline: 5.5703x; 1.0331x over previous
//
#include <hip/hip_runtime.h>
#include <hip/hip_bf16.h>

#define DIM 64
#define NRELS 8
#define NBASES 4
#define NW 9              // 8 relations + self
#define BKT_SHIFT 7
#define BKT_NODES 128     // nodes per bucket
#define MAXBKT 1024
#define P1_CHUNK 2048
#define P3_CHUNK 4096

typedef __attribute__((ext_vector_type(8))) short short8;
typedef __attribute__((ext_vector_type(4))) float f32x4;

__device__ inline unsigned short f2bf(float f) {
    union { float f; unsigned int u; } v; v.f = f;
    unsigned int u = v.u;
    unsigned int r = u + 0x7FFFu + ((u >> 16) & 1u);  // round-to-nearest-even
    return (unsigned short)(r >> 16);
}
__device__ inline float bf2f(unsigned short s) {
    union { unsigned int u; float f; } v; v.u = ((unsigned int)s) << 16;
    return v.f;
}

// Pack BOTH layers' W matrices into MFMA B-fragment order, bf16. Also zero-inits bktcnt.
// B element for mfma_f32_16x16x32_bf16: k = half*32 + (lane>>4)*8 + e, j = jt*16 + (lane&15)
__global__ void build_wpk2(const float* __restrict__ bases1, const float* __restrict__ coef1,
                           const float* __restrict__ wself1, unsigned short* __restrict__ Wpk1,
                           const float* __restrict__ bases2, const float* __restrict__ coef2,
                           const float* __restrict__ wself2, unsigned short* __restrict__ Wpk2,
                           int* __restrict__ bktcnt) {
    int idx = blockIdx.x * blockDim.x + threadIdx.x;
    if (idx < MAXBKT) bktcnt[idx] = 0;
    if (idx >= 2 * NW * DIM * DIM) return;
    int set = (idx >= NW * DIM * DIM);
    const float* bases = set ? bases2 : bases1;
    const float* coef  = set ? coef2 : coef1;
    const float* wself = set ? wself2 : wself1;
    unsigned short* Wpk = set ? Wpk2 : Wpk1;
    idx -= set * NW * DIM * DIM;
    int r = idx >> 12;
    int k = (idx >> 6) & 63;
    int j = idx & 63;
    float v;
    if (r < NRELS) {
        v = 0.f;
#pragma unroll
        for (int b = 0; b < NBASES; ++b)
            v += coef[r * NBASES + b] * bases[((size_t)b * DIM + k) * DIM + j];
    } else {
        v = wself[k * DIM + j];
    }
    int half = k >> 5, e = k & 7, laneHi = (k >> 3) & 3;
    int jt = j >> 4, laneLo = j & 15;
    int lane = laneHi * 16 + laneLo;
    Wpk[(size_t)((((r * 4 + jt) * 2 + half) * 64 + lane) * 8 + e)] = f2bf(v);
}

// Per 64-node tile (4 waves x 16 nodes), NO LDS, relation-split across 2x blocks:
//   blocks [0, nbh)        : relations 0..3  + self
//   blocks [nbh, 2*nbh)    : relations 4..7
//   hproj rows stored fragment-permuted: ushort position lrow*4 + jt <-> col jt*16 + lrow.
__global__ __launch_bounds__(256) void proj_kernel(const float* __restrict__ h,
                                                   const unsigned short* __restrict__ Wpk,
                                                   const float* __restrict__ bias,
                                                   unsigned short* __restrict__ hproj,
                                                   float* __restrict__ selfbuf, int n_nodes,
                                                   int nbh) {
    const int half_id = (blockIdx.x >= nbh);
    const int tb = half_id ? (blockIdx.x - nbh) : blockIdx.x;
    const int lane = threadIdx.x & 63;
    const int wave = threadIdx.x >> 6;
    const int n0 = tb * 64 + wave * 16;
    if (n0 >= n_nodes) return;
    const int lrow = lane & 15;
    const int lhi = lane >> 4;

    int row = n0 + lrow;
    if (row >= n_nodes) row = n_nodes - 1;
    const float* hrow = h + (size_t)row * DIM + lhi * 8;
    float4 x0 = *(const float4*)(hrow);
    float4 x1 = *(const float4*)(hrow + 4);
    float4 x2 = *(const float4*)(hrow + 32);
    float4 x3 = *(const float4*)(hrow + 36);
    short8 a0, a1;
    a0[0] = (short)f2bf(x0.x); a0[1] = (short)f2bf(x0.y);
    a0[2] = (short)f2bf(x0.z); a0[3] = (short)f2bf(x0.w);
    a0[4] = (short)f2bf(x1.x); a0[5] = (short)f2bf(x1.y);
    a0[6] = (short)f2bf(x1.z); a0[7] = (short)f2bf(x1.w);
    a1[0] = (short)f2bf(x2.x); a1[1] = (short)f2bf(x2.y);
    a1[2] = (short)f2bf(x2.z); a1[3] = (short)f2bf(x2.w);
    a1[4] = (short)f2bf(x3.x); a1[5] = (short)f2bf(x3.y);
    a1[6] = (short)f2bf(x3.z); a1[7] = (short)f2bf(x3.w);

    const size_t nn = (size_t)n_nodes;
    const int rbeg = half_id ? 4 : 0;
    const int rend = half_id ? NRELS : 4;

    for (int r = rbeg; r < rend; ++r) {
        f32x4 c[4];
#pragma unroll
        for (int jt = 0; jt < 4; ++jt) {
            const unsigned short* bbase = Wpk + (size_t)(((r * 4 + jt) * 2) * 64 + lane) * 8;
            short8 b0 = *(const short8*)bbase;
            short8 b1 = *(const short8*)(bbase + 512);
            f32x4 cc = {0.f, 0.f, 0.f, 0.f};
            cc = __builtin_amdgcn_mfma_f32_16x16x32_bf16(a0, b0, cc, 0, 0, 0);
            cc = __builtin_amdgcn_mfma_f32_16x16x32_bf16(a1, b1, cc, 0, 0, 0);
            c[jt] = cc;
        }
        // permuted row store: node = n0 + lhi*4 + reg; 8B at ushort offset lrow*4
        unsigned short* rb = hproj + ((size_t)r * nn + (size_t)(n0 + lhi * 4)) * DIM + lrow * 4;
#pragma unroll
        for (int reg = 0; reg < 4; ++reg) {
            if (n0 + lhi * 4 + reg < n_nodes) {
                unsigned lo = (unsigned)f2bf(c[0][reg]) | ((unsigned)f2bf(c[1][reg]) << 16);
                unsigned hi = (unsigned)f2bf(c[2][reg]) | ((unsigned)f2bf(c[3][reg]) << 16);
                uint2 v; v.x = lo; v.y = hi;
                *(uint2*)(rb + (size_t)reg * DIM) = v;
            }
        }
    }

    if (!half_id) {
        // self projection (true column order) + bias
        f32x4 c[4];
#pragma unroll
        for (int jt = 0; jt < 4; ++jt) {
            const unsigned short* bbase = Wpk + (size_t)(((NRELS * 4 + jt) * 2) * 64 + lane) * 8;
            short8 b0 = *(const short8*)bbase;
            short8 b1 = *(const short8*)(bbase + 512);
            f32x4 cc = {0.f, 0.f, 0.f, 0.f};
            cc = __builtin_amdgcn_mfma_f32_16x16x32_bf16(a0, b0, cc, 0, 0, 0);
            cc = __builtin_amdgcn_mfma_f32_16x16x32_bf16(a1, b1, cc, 0, 0, 0);
            c[jt] = cc;
        }
#pragma unroll
        for (int jt = 0; jt < 4; ++jt) {
            int j = jt * 16 + lrow;
            float bj = bias[j];
            float* op = selfbuf + (size_t)n0 * DIM + j;
#pragma unroll
            for (int reg = 0; reg < 4; ++reg) {
                int i = lhi * 4 + reg;
                if (n0 + i < n_nodes) op[(size_t)i * DIM] = c[jt][reg] + bj;
            }
        }
    }
}

// ---- two-level CSR build ----

__global__ __launch_bounds__(256) void bucket_count(const int* __restrict__ dst,
                                                    int* __restrict__ bktcnt,
                                                    int n_edges, int nbkt) {
    __shared__ int h[MAXBKT];
    int t = threadIdx.x;
    for (int i = t; i < nbkt; i += 256) h[i] = 0;
    __syncthreads();
    int e0 = blockIdx.x * P1_CHUNK;
#pragma unroll
    for (int k = 0; k < P1_CHUNK / 256; ++k) {
        int e = e0 + k * 256 + t;
        if (e < n_edges) atomicAdd(&h[dst[e] >> BKT_SHIFT], 1);
    }
    __syncthreads();
    for (int i = t; i < nbkt; i += 256)
        if (h[i]) atomicAdd(&bktcnt[i], h[i]);
}

__global__ __launch_bounds__(1024) void scan_bkt(const int* __restrict__ cnt,
                                                 int* __restrict__ off,
                                                 int* __restrict__ pos, int nbkt) {
    __shared__ int a[1024], b[1024];
    int t = threadIdx.x;
    int v = (t < nbkt) ? cnt[t] : 0;
    a[t] = v;
    __syncthreads();
    int* pin = a;
    int* pout = b;
    for (int d = 1; d < 1024; d <<= 1) {
        pout[t] = pin[t] + ((t >= d) ? pin[t - d] : 0);
        __syncthreads();
        int* tmp = pin; pin = pout; pout = tmp;
    }
    int incl = pin[t];
    int excl = incl - v;
    if (t < nbkt) { off[t] = excl; pos[t] = excl; }
    if (t == 1023) off[nbkt] = incl;
}

// Partition edges into bucket-contiguous perm_tmp, packed src | et<<17 | dstlow<<20
__global__ __launch_bounds__(256) void partition(const int* __restrict__ src,
                                                 const int* __restrict__ dst,
                                                 const int* __restrict__ et,
                                                 int* __restrict__ bktpos,
                                                 unsigned* __restrict__ perm_tmp,
                                                 int n_edges, int nbkt) {
    __shared__ int h[MAXBKT];
    __shared__ int base[MAXBKT];
    int t = threadIdx.x;
    for (int i = t; i < nbkt; i += 256) h[i] = 0;
    __syncthreads();
    int e0 = blockIdx.x * P3_CHUNK;
#pragma unroll
    for (int k = 0; k < P3_CHUNK / 256; ++k) {
        int e = e0 + k * 256 + t;
        if (e < n_edges) atomicAdd(&h[dst[e] >> BKT_SHIFT], 1);
    }
    __syncthreads();
    for (int i = t; i < nbkt; i += 256) {
        int c = h[i];
        base[i] = c ? atomicAdd(&bktpos[i], c) : 0;
        h[i] = 0;
    }
    __syncthreads();
#pragma unroll
    for (int k = 0; k < P3_CHUNK / 256; ++k) {
        int e = e0 + k * 256 + t;
        if (e < n_edges) {
            int d = dst[e];
            int bk = d >> BKT_SHIFT;
            int rk = atomicAdd(&h[bk], 1);
            perm_tmp[base[bk] + rk] =
                (unsigned)src[e] | ((unsigned)et[e] << 17) | ((unsigned)(d & (BKT_NODES - 1)) << 20);
        }
    }
}

// One block per bucket: exact per-dst CSR. Emits doff[] and dst-sorted perm (src|et, 20 bits).
__global__ __launch_bounds__(256) void bucket_csr(const unsigned* __restrict__ perm_tmp,
                                                  const int* __restrict__ bktoff,
                                                  unsigned* __restrict__ perm,
                                                  int* __restrict__ doff, int n_nodes) {
    __shared__ int h[BKT_NODES];
    __shared__ int sa[BKT_NODES], sb[BKT_NODES];
    __shared__ int lpos[BKT_NODES];
    const int t = threadIdx.x;
    const int b = blockIdx.x;
    const int beg = bktoff[b], end = bktoff[b + 1];
    if (t < BKT_NODES) h[t] = 0;
    __syncthreads();
    for (int i = beg + t; i < end; i += 256) atomicAdd(&h[perm_tmp[i] >> 20], 1);
    __syncthreads();
    int v = (t < BKT_NODES) ? h[t] : 0;
    if (t < BKT_NODES) sa[t] = v;
    __syncthreads();
    int* pin = sa;
    int* pout = sb;
    for (int d = 1; d < BKT_NODES; d <<= 1) {
        if (t < BKT_NODES) pout[t] = pin[t] + ((t >= d) ? pin[t - d] : 0);
        __syncthreads();
        int* tmp = pin; pin = pout; pout = tmp;
    }
    if (t < BKT_NODES) {
        int excl = pin[t] - v;
        lpos[t] = beg + excl;
        int dnode = b * BKT_NODES + t;
        if (dnode < n_nodes) doff[dnode] = beg + excl;
    }
    if (b == gridDim.x - 1 && t == 0) doff[n_nodes] = end;
    __syncthreads();
    for (int i = beg + t; i < end; i += 256) {
        unsigned rc = perm_tmp[i];
        int p = atomicAdd(&lpos[rc >> 20], 1);
        perm[p] = rc & 0xFFFFFu;  // src | et<<17
    }
}

// gather7: one wave per dst. Perm entries preloaded 64-at-a-time into a register
// (one coalesced load covers deg<=64), broadcast via __shfl; 32 edges (4 independent
// uint4 row loads per lane) in flight per inner iteration. Rows are fragment-permuted.
__global__ __launch_bounds__(256) void gather7(const unsigned* __restrict__ perm,
                                               const int* __restrict__ doff,
                                               const unsigned short* __restrict__ hproj,
                                               const float* __restrict__ selfbuf,
                                               float* __restrict__ out, int n_nodes) {
    int gid = blockIdx.x * blockDim.x + threadIdx.x;
    int d = gid >> 6;
    if (d >= n_nodes) return;
    int lane = gid & 63;
    int g = lane >> 3;   // edge slot 0..7
    int s = lane & 7;    // 16B chunk index within row
    int beg = doff[d], end = doff[d + 1];
    int deg = end - beg;
    const size_t nn = (size_t)n_nodes;

    float acc[8];
#pragma unroll
    for (int k = 0; k < 8; ++k) acc[k] = 0.f;

    for (int base = 0; base < deg; base += 64) {
        unsigned pv = (beg + base + lane < end) ? perm[beg + base + lane] : 0u;
        int m = min(64, deg - base);
        for (int i = 0; i < m; i += 32) {
            uint4 v0 = make_uint4(0u, 0u, 0u, 0u);
            uint4 v1 = make_uint4(0u, 0u, 0u, 0u);
            uint4 v2 = make_uint4(0u, 0u, 0u, 0u);
            uint4 v3 = make_uint4(0u, 0u, 0u, 0u);
            int i0 = i + g, i1 = i + 8 + g, i2 = i + 16 + g, i3 = i + 24 + g;
            unsigned rc0 = __shfl(pv, i0);
            unsigned rc1 = __shfl(pv, i1);
            unsigned rc2 = __shfl(pv, i2);
            unsigned rc3 = __shfl(pv, i3);
            if (i0 < m) v0 = *(const uint4*)(hproj + ((size_t)(rc0 >> 17) * nn + (rc0 & 0x1FFFFu)) * DIM + s * 8);
            if (i1 < m) v1 = *(const uint4*)(hproj + ((size_t)(rc1 >> 17) * nn + (rc1 & 0x1FFFFu)) * DIM + s * 8);
            if (i2 < m) v2 = *(const uint4*)(hproj + ((size_t)(rc2 >> 17) * nn + (rc2 & 0x1FFFFu)) * DIM + s * 8);
            if (i3 < m) v3 = *(const uint4*)(hproj + ((size_t)(rc3 >> 17) * nn + (rc3 & 0x1FFFFu)) * DIM + s * 8);
            acc[0] += bf2f((unsigned short)(v0.x & 0xFFFFu)); acc[1] += bf2f((unsigned short)(v0.x >> 16));
            acc[2] += bf2f((unsigned short)(v0.y & 0xFFFFu)); acc[3] += bf2f((unsigned short)(v0.y >> 16));
            acc[4] += bf2f((unsigned short)(v0.z & 0xFFFFu)); acc[5] += bf2f((unsigned short)(v0.z >> 16));
            acc[6] += bf2f((unsigned short)(v0.w & 0xFFFFu)); acc[7] += bf2f((unsigned short)(v0.w >> 16));
            acc[0] += bf2f((unsigned short)(v1.x & 0xFFFFu)); acc[1] += bf2f((unsigned short)(v1.x >> 16));
            acc[2] += bf2f((unsigned short)(v1.y & 0xFFFFu)); acc[3] += bf2f((unsigned short)(v1.y >> 16));
            acc[4] += bf2f((unsigned short)(v1.z & 0xFFFFu)); acc[5] += bf2f((unsigned short)(v1.z >> 16));
            acc[6] += bf2f((unsigned short)(v1.w & 0xFFFFu)); acc[7] += bf2f((unsigned short)(v1.w >> 16));
            acc[0] += bf2f((unsigned short)(v2.x & 0xFFFFu)); acc[1] += bf2f((unsigned short)(v2.x >> 16));
            acc[2] += bf2f((unsigned short)(v2.y & 0xFFFFu)); acc[3] += bf2f((unsigned short)(v2.y >> 16));
            acc[4] += bf2f((unsigned short)(v2.z & 0xFFFFu)); acc[5] += bf2f((unsigned short)(v2.z >> 16));
            acc[6] += bf2f((unsigned short)(v2.w & 0xFFFFu)); acc[7] += bf2f((unsigned short)(v2.w >> 16));
            acc[0] += bf2f((unsigned short)(v3.x & 0xFFFFu)); acc[1] += bf2f((unsigned short)(v3.x >> 16));
            acc[2] += bf2f((unsigned short)(v3.y & 0xFFFFu)); acc[3] += bf2f((unsigned short)(v3.y >> 16));
            acc[4] += bf2f((unsigned short)(v3.z & 0xFFFFu)); acc[5] += bf2f((unsigned short)(v3.z >> 16));
            acc[6] += bf2f((unsigned short)(v3.w & 0xFFFFu)); acc[7] += bf2f((unsigned short)(v3.w >> 16));
        }
    }
    // reduce across the 8 edge slots (lanes with equal s)
#pragma unroll
    for (int k = 0; k < 8; ++k) {
        acc[k] += __shfl_xor(acc[k], 8);
        acc[k] += __shfl_xor(acc[k], 16);
        acc[k] += __shfl_xor(acc[k], 32);
    }
    if (g == 0) {
        // acc[u]: position s*8+u of permuted row = col (u&3)*16 + 2s + (u>>2)
#pragma unroll
        for (int jt = 0; jt < 4; ++jt) {
            const float2 sv = *(const float2*)(selfbuf + (size_t)d * DIM + jt * 16 + 2 * s);
            float2 o; o.x = acc[jt] + sv.x; o.y = acc[4 + jt] + sv.y;
            *(float2*)(out + (size_t)d * DIM + jt * 16 + 2 * s) = o;
        }
    }
}

extern "C" void kernel_launch(void* const* d_in, const int* in_sizes, int n_in,
                              void* d_out, int out_size, void* d_ws, size_t ws_size,
                              hipStream_t stream) {
    const int* src = (const int*)d_in[0];
    const int* dst = (const int*)d_in[1];
    const int* et  = (const int*)d_in[2];
    const float* emb    = (const float*)d_in[3];
    const float* bases1 = (const float*)d_in[4];
    const float* coef1  = (const float*)d_in[5];
    const float* wself1 = (const float*)d_in[6];
    const float* bias1  = (const float*)d_in[7];
    const float* bases2 = (const float*)d_in[8];
    const float* coef2  = (const float*)d_in[9];
    const float* wself2 = (const float*)d_in[10];
    const float* bias2  = (const float*)d_in[11];
    float* out = (float*)d_out;

    const int NE = in_sizes[0];
    const int NN = in_sizes[3] / DIM;
    const int NBKT = (NN + BKT_NODES - 1) / BKT_NODES;  // 782

    // Workspace: Wpk1|Wpk2|selfbuf|h1|hproj|bktcnt|bktoff|bktpos|doff|perm_tmp|perm  (~164 MB)
    unsigned short* Wpk1 = (unsigned short*)d_ws;
    unsigned short* Wpk2 = Wpk1 + (size_t)NW * DIM * DIM;
    float* selfbuf = (float*)(Wpk2 + (size_t)NW * DIM * DIM);
    float* h1 = selfbuf + (size_t)NN * DIM;
    unsigned short* hproj = (unsigned short*)(h1 + (size_t)NN * DIM);
    int* bktcnt = (int*)(hproj + (size_t)NRELS * NN * DIM);
    int* bktoff = bktcnt + MAXBKT;
    int* bktpos = bktoff + MAXBKT + 1;
    int* doff = bktpos + MAXBKT;
    unsigned* perm_tmp = (unsigned*)(doff + NN + 64);
    unsigned* perm = perm_tmp + NE;

    const int wpk_threads = 2 * NW * DIM * DIM;
    build_wpk2<<<(wpk_threads + 255) / 256, 256, 0, stream>>>(bases1, coef1, wself1, Wpk1,
                                                              bases2, coef2, wself2, Wpk2,
                                                              bktcnt);

    bucket_count<<<(NE + P1_CHUNK - 1) / P1_CHUNK, 256, 0, stream>>>(dst, bktcnt, NE, NBKT);
    scan_bkt<<<1, 1024, 0, stream>>>(bktcnt, bktoff, bktpos, NBKT);
    partition<<<(NE + P3_CHUNK - 1) / P3_CHUNK, 256, 0, stream>>>(src, dst, et, bktpos, perm_tmp, NE, NBKT);
    bucket_csr<<<NBKT, 256, 0, stream>>>(perm_tmp, bktoff, perm, doff, NN);

    const int proj_blocks = (NN + 63) / 64;
    const int gath_blocks = (NN + 3) / 4;  // one wave per dst

    // Layer 1
    proj_kernel<<<2 * proj_blocks, 256, 0, stream>>>(emb, Wpk1, bias1, hproj, selfbuf, NN, proj_blocks);
    gather7<<<gath_blocks, 256, 0, stream>>>(perm, doff, hproj, selfbuf, h1, NN);

    // Layer 2
    proj_kernel<<<2 * proj_blocks, 256, 0, stream>>>(h1, Wpk2, bias2, hproj, selfbuf, NN, proj_blocks);
    gather7<<<gath_blocks, 256, 0, stream>>>(perm, doff, hproj, selfbuf, out, NN);
}

// Round 11
// 186.061 us; speedup vs baseline: 6.2503x; 1.1221x over previous
//
#include <hip/hip_runtime.h>
#include <hip/hip_bf16.h>

#define DIM 64
#define NRELS 8
#define NBASES 4
#define NW 9              // 8 relations + self (stored as relation 8)
#define BKT_SHIFT 7
#define BKT_NODES 128     // nodes per bucket
#define MAXBKT 1024
#define CAP 4096          // fixed per-bucket edge capacity (mean 1535 for this input; P(>4096)~0)
#define P3_CHUNK 4096

typedef __attribute__((ext_vector_type(8))) short short8;
typedef __attribute__((ext_vector_type(4))) float f32x4;

__device__ inline unsigned short f2bf(float f) {
    union { float f; unsigned int u; } v; v.f = f;
    unsigned int u = v.u;
    unsigned int r = u + 0x7FFFu + ((u >> 16) & 1u);  // round-to-nearest-even
    return (unsigned short)(r >> 16);
}
__device__ inline float bf2f(unsigned short s) {
    union { unsigned int u; float f; } v; v.u = ((unsigned int)s) << 16;
    return v.f;
}

// Pack BOTH layers' W matrices (8 relation + wself as r=8) into MFMA B-fragment order,
// bf16. Also zero-inits bktpos.
// B element for mfma_f32_16x16x32_bf16: k = half*32 + (lane>>4)*8 + e, j = jt*16 + (lane&15)
__global__ void build_wpk2(const float* __restrict__ bases1, const float* __restrict__ coef1,
                           const float* __restrict__ wself1, unsigned short* __restrict__ Wpk1,
                           const float* __restrict__ bases2, const float* __restrict__ coef2,
                           const float* __restrict__ wself2, unsigned short* __restrict__ Wpk2,
                           int* __restrict__ bktpos) {
    int idx = blockIdx.x * blockDim.x + threadIdx.x;
    if (idx < MAXBKT) bktpos[idx] = 0;
    if (idx >= 2 * NW * DIM * DIM) return;
    int set = (idx >= NW * DIM * DIM);
    const float* bases = set ? bases2 : bases1;
    const float* coef  = set ? coef2 : coef1;
    const float* wself = set ? wself2 : wself1;
    unsigned short* Wpk = set ? Wpk2 : Wpk1;
    idx -= set * NW * DIM * DIM;
    int r = idx >> 12;
    int k = (idx >> 6) & 63;
    int j = idx & 63;
    float v;
    if (r < NRELS) {
        v = 0.f;
#pragma unroll
        for (int b = 0; b < NBASES; ++b)
            v += coef[r * NBASES + b] * bases[((size_t)b * DIM + k) * DIM + j];
    } else {
        v = wself[k * DIM + j];
    }
    int half = k >> 5, e = k & 7, laneHi = (k >> 3) & 3;
    int jt = j >> 4, laneLo = j & 15;
    int lane = laneHi * 16 + laneLo;
    Wpk[(size_t)((((r * 4 + jt) * 2 + half) * 64 + lane) * 8 + e)] = f2bf(v);
}

// Per 64-node tile (4 waves x 16 nodes), NO LDS, relation-split across 2x blocks:
//   blocks [0, nbh): relations 0..4;  blocks [nbh, 2*nbh): relations 5..8 (8 = self).
//   All NW planes stored fragment-permuted: ushort position lrow*4 + jt <-> col jt*16 + lrow.
__global__ __launch_bounds__(256) void proj_kernel(const float* __restrict__ h,
                                                   const unsigned short* __restrict__ Wpk,
                                                   unsigned short* __restrict__ hproj,
                                                   int n_nodes, int nbh) {
    const int half_id = (blockIdx.x >= nbh);
    const int tb = half_id ? (blockIdx.x - nbh) : blockIdx.x;
    const int lane = threadIdx.x & 63;
    const int wave = threadIdx.x >> 6;
    const int n0 = tb * 64 + wave * 16;
    if (n0 >= n_nodes) return;
    const int lrow = lane & 15;
    const int lhi = lane >> 4;

    int row = n0 + lrow;
    if (row >= n_nodes) row = n_nodes - 1;
    const float* hrow = h + (size_t)row * DIM + lhi * 8;
    float4 x0 = *(const float4*)(hrow);
    float4 x1 = *(const float4*)(hrow + 4);
    float4 x2 = *(const float4*)(hrow + 32);
    float4 x3 = *(const float4*)(hrow + 36);
    short8 a0, a1;
    a0[0] = (short)f2bf(x0.x); a0[1] = (short)f2bf(x0.y);
    a0[2] = (short)f2bf(x0.z); a0[3] = (short)f2bf(x0.w);
    a0[4] = (short)f2bf(x1.x); a0[5] = (short)f2bf(x1.y);
    a0[6] = (short)f2bf(x1.z); a0[7] = (short)f2bf(x1.w);
    a1[0] = (short)f2bf(x2.x); a1[1] = (short)f2bf(x2.y);
    a1[2] = (short)f2bf(x2.z); a1[3] = (short)f2bf(x2.w);
    a1[4] = (short)f2bf(x3.x); a1[5] = (short)f2bf(x3.y);
    a1[6] = (short)f2bf(x3.z); a1[7] = (short)f2bf(x3.w);

    const size_t nn = (size_t)n_nodes;
    const int rbeg = half_id ? 5 : 0;
    const int rend = half_id ? NW : 5;

    for (int r = rbeg; r < rend; ++r) {
        f32x4 c[4];
#pragma unroll
        for (int jt = 0; jt < 4; ++jt) {
            const unsigned short* bbase = Wpk + (size_t)(((r * 4 + jt) * 2) * 64 + lane) * 8;
            short8 b0 = *(const short8*)bbase;
            short8 b1 = *(const short8*)(bbase + 512);
            f32x4 cc = {0.f, 0.f, 0.f, 0.f};
            cc = __builtin_amdgcn_mfma_f32_16x16x32_bf16(a0, b0, cc, 0, 0, 0);
            cc = __builtin_amdgcn_mfma_f32_16x16x32_bf16(a1, b1, cc, 0, 0, 0);
            c[jt] = cc;
        }
        // permuted row store: node = n0 + lhi*4 + reg; 8B at ushort offset lrow*4
        unsigned short* rb = hproj + ((size_t)r * nn + (size_t)(n0 + lhi * 4)) * DIM + lrow * 4;
#pragma unroll
        for (int reg = 0; reg < 4; ++reg) {
            if (n0 + lhi * 4 + reg < n_nodes) {
                unsigned lo = (unsigned)f2bf(c[0][reg]) | ((unsigned)f2bf(c[1][reg]) << 16);
                unsigned hi = (unsigned)f2bf(c[2][reg]) | ((unsigned)f2bf(c[3][reg]) << 16);
                uint2 v; v.x = lo; v.y = hi;
                *(uint2*)(rb + (size_t)reg * DIM) = v;
            }
        }
    }
}

// Partition edges into fixed-stride buckets perm_tmp[b*CAP + ...], packed
// src | et<<17 | dstlow<<20. bktpos[b] ends as the bucket's edge count.
__global__ __launch_bounds__(256) void partition2(const int* __restrict__ src,
                                                  const int* __restrict__ dst,
                                                  const int* __restrict__ et,
                                                  int* __restrict__ bktpos,
                                                  unsigned* __restrict__ perm_tmp,
                                                  int n_edges, int nbkt) {
    __shared__ int h[MAXBKT];
    __shared__ int base[MAXBKT];
    int t = threadIdx.x;
    for (int i = t; i < nbkt; i += 256) h[i] = 0;
    __syncthreads();
    int e0 = blockIdx.x * P3_CHUNK;
#pragma unroll
    for (int k = 0; k < P3_CHUNK / 256; ++k) {
        int e = e0 + k * 256 + t;
        if (e < n_edges) atomicAdd(&h[dst[e] >> BKT_SHIFT], 1);
    }
    __syncthreads();
    for (int i = t; i < nbkt; i += 256) {
        int c = h[i];
        base[i] = c ? atomicAdd(&bktpos[i], c) : 0;
        h[i] = 0;
    }
    __syncthreads();
#pragma unroll
    for (int k = 0; k < P3_CHUNK / 256; ++k) {
        int e = e0 + k * 256 + t;
        if (e < n_edges) {
            int d = dst[e];
            int bk = d >> BKT_SHIFT;
            int rk = atomicAdd(&h[bk], 1);
            perm_tmp[(size_t)bk * CAP + base[bk] + rk] =
                (unsigned)src[e] | ((unsigned)et[e] << 17) | ((unsigned)(d & (BKT_NODES - 1)) << 20);
        }
    }
}

// One block per bucket: per-dst CSR within the fixed-stride bucket. Emits absolute
// doff/dend per node and dst-sorted perm (src|et<<17, 20 bits) at perm[b*CAP + ...].
__global__ __launch_bounds__(256) void bucket_csr2(const unsigned* __restrict__ perm_tmp,
                                                   const int* __restrict__ bktpos,
                                                   unsigned* __restrict__ perm,
                                                   int* __restrict__ doff, int* __restrict__ dend,
                                                   int n_nodes) {
    __shared__ int h[BKT_NODES];
    __shared__ int sa[BKT_NODES], sb[BKT_NODES];
    __shared__ int lpos[BKT_NODES];
    const int t = threadIdx.x;
    const int b = blockIdx.x;
    const int cnt = bktpos[b];
    const size_t bb = (size_t)b * CAP;
    if (t < BKT_NODES) h[t] = 0;
    __syncthreads();
    for (int i = t; i < cnt; i += 256) atomicAdd(&h[perm_tmp[bb + i] >> 20], 1);
    __syncthreads();
    int v = (t < BKT_NODES) ? h[t] : 0;
    if (t < BKT_NODES) sa[t] = v;
    __syncthreads();
    int* pin = sa;
    int* pout = sb;
    for (int d = 1; d < BKT_NODES; d <<= 1) {
        if (t < BKT_NODES) pout[t] = pin[t] + ((t >= d) ? pin[t - d] : 0);
        __syncthreads();
        int* tmp = pin; pin = pout; pout = tmp;
    }
    if (t < BKT_NODES) {
        int excl = pin[t] - v;
        lpos[t] = excl;
        int dnode = b * BKT_NODES + t;
        if (dnode < n_nodes) {
            doff[dnode] = b * CAP + excl;
            dend[dnode] = b * CAP + excl + v;
        }
    }
    __syncthreads();
    for (int i = t; i < cnt; i += 256) {
        unsigned rc = perm_tmp[bb + i];
        int p = atomicAdd(&lpos[rc >> 20], 1);
        perm[bb + p] = rc & 0xFFFFFu;  // src | et<<17
    }
}

// gather8: one wave per dst. Self term read from hproj plane 8; bias applied in
// epilogue. Perm entries preloaded 64-at-a-time (coalesced), broadcast via __shfl;
// 32 edges (4 independent uint4 row loads per lane) in flight. Rows fragment-permuted.
__global__ __launch_bounds__(256) void gather8(const unsigned* __restrict__ perm,
                                               const int* __restrict__ doff,
                                               const int* __restrict__ dend,
                                               const unsigned short* __restrict__ hproj,
                                               const float* __restrict__ bias,
                                               float* __restrict__ out, int n_nodes) {
    int gid = blockIdx.x * blockDim.x + threadIdx.x;
    int d = gid >> 6;
    if (d >= n_nodes) return;
    int lane = gid & 63;
    int g = lane >> 3;   // edge slot 0..7
    int s = lane & 7;    // 16B chunk index within row
    int beg = doff[d], end = dend[d];
    int deg = end - beg;
    const size_t nn = (size_t)n_nodes;

    float acc[8];
#pragma unroll
    for (int k = 0; k < 8; ++k) acc[k] = 0.f;

    // self term (relation plane 8): one 8-lane group reads the row; reduce folds it in
    if (g == 0) {
        const uint4 v = *(const uint4*)(hproj + ((size_t)NRELS * nn + (size_t)d) * DIM + s * 8);
        acc[0] += bf2f((unsigned short)(v.x & 0xFFFFu)); acc[1] += bf2f((unsigned short)(v.x >> 16));
        acc[2] += bf2f((unsigned short)(v.y & 0xFFFFu)); acc[3] += bf2f((unsigned short)(v.y >> 16));
        acc[4] += bf2f((unsigned short)(v.z & 0xFFFFu)); acc[5] += bf2f((unsigned short)(v.z >> 16));
        acc[6] += bf2f((unsigned short)(v.w & 0xFFFFu)); acc[7] += bf2f((unsigned short)(v.w >> 16));
    }

    for (int base = 0; base < deg; base += 64) {
        unsigned pv = (beg + base + lane < end) ? perm[beg + base + lane] : 0u;
        int m = min(64, deg - base);
        for (int i = 0; i < m; i += 32) {
            uint4 v0 = make_uint4(0u, 0u, 0u, 0u);
            uint4 v1 = make_uint4(0u, 0u, 0u, 0u);
            uint4 v2 = make_uint4(0u, 0u, 0u, 0u);
            uint4 v3 = make_uint4(0u, 0u, 0u, 0u);
            int i0 = i + g, i1 = i + 8 + g, i2 = i + 16 + g, i3 = i + 24 + g;
            unsigned rc0 = __shfl(pv, i0);
            unsigned rc1 = __shfl(pv, i1);
            unsigned rc2 = __shfl(pv, i2);
            unsigned rc3 = __shfl(pv, i3);
            if (i0 < m) v0 = *(const uint4*)(hproj + ((size_t)(rc0 >> 17) * nn + (rc0 & 0x1FFFFu)) * DIM + s * 8);
            if (i1 < m) v1 = *(const uint4*)(hproj + ((size_t)(rc1 >> 17) * nn + (rc1 & 0x1FFFFu)) * DIM + s * 8);
            if (i2 < m) v2 = *(const uint4*)(hproj + ((size_t)(rc2 >> 17) * nn + (rc2 & 0x1FFFFu)) * DIM + s * 8);
            if (i3 < m) v3 = *(const uint4*)(hproj + ((size_t)(rc3 >> 17) * nn + (rc3 & 0x1FFFFu)) * DIM + s * 8);
            acc[0] += bf2f((unsigned short)(v0.x & 0xFFFFu)); acc[1] += bf2f((unsigned short)(v0.x >> 16));
            acc[2] += bf2f((unsigned short)(v0.y & 0xFFFFu)); acc[3] += bf2f((unsigned short)(v0.y >> 16));
            acc[4] += bf2f((unsigned short)(v0.z & 0xFFFFu)); acc[5] += bf2f((unsigned short)(v0.z >> 16));
            acc[6] += bf2f((unsigned short)(v0.w & 0xFFFFu)); acc[7] += bf2f((unsigned short)(v0.w >> 16));
            acc[0] += bf2f((unsigned short)(v1.x & 0xFFFFu)); acc[1] += bf2f((unsigned short)(v1.x >> 16));
            acc[2] += bf2f((unsigned short)(v1.y & 0xFFFFu)); acc[3] += bf2f((unsigned short)(v1.y >> 16));
            acc[4] += bf2f((unsigned short)(v1.z & 0xFFFFu)); acc[5] += bf2f((unsigned short)(v1.z >> 16));
            acc[6] += bf2f((unsigned short)(v1.w & 0xFFFFu)); acc[7] += bf2f((unsigned short)(v1.w >> 16));
            acc[0] += bf2f((unsigned short)(v2.x & 0xFFFFu)); acc[1] += bf2f((unsigned short)(v2.x >> 16));
            acc[2] += bf2f((unsigned short)(v2.y & 0xFFFFu)); acc[3] += bf2f((unsigned short)(v2.y >> 16));
            acc[4] += bf2f((unsigned short)(v2.z & 0xFFFFu)); acc[5] += bf2f((unsigned short)(v2.z >> 16));
            acc[6] += bf2f((unsigned short)(v2.w & 0xFFFFu)); acc[7] += bf2f((unsigned short)(v2.w >> 16));
            acc[0] += bf2f((unsigned short)(v3.x & 0xFFFFu)); acc[1] += bf2f((unsigned short)(v3.x >> 16));
            acc[2] += bf2f((unsigned short)(v3.y & 0xFFFFu)); acc[3] += bf2f((unsigned short)(v3.y >> 16));
            acc[4] += bf2f((unsigned short)(v3.z & 0xFFFFu)); acc[5] += bf2f((unsigned short)(v3.z >> 16));
            acc[6] += bf2f((unsigned short)(v3.w & 0xFFFFu)); acc[7] += bf2f((unsigned short)(v3.w >> 16));
        }
    }
    // reduce across the 8 edge slots (lanes with equal s)
#pragma unroll
    for (int k = 0; k < 8; ++k) {
        acc[k] += __shfl_xor(acc[k], 8);
        acc[k] += __shfl_xor(acc[k], 16);
        acc[k] += __shfl_xor(acc[k], 32);
    }
    if (g == 0) {
        // acc[u]: position s*8+u of permuted row = col (u&3)*16 + 2s + (u>>2)
#pragma unroll
        for (int jt = 0; jt < 4; ++jt) {
            const float2 bv = *(const float2*)(bias + jt * 16 + 2 * s);
            float2 o; o.x = acc[jt] + bv.x; o.y = acc[4 + jt] + bv.y;
            *(float2*)(out + (size_t)d * DIM + jt * 16 + 2 * s) = o;
        }
    }
}

extern "C" void kernel_launch(void* const* d_in, const int* in_sizes, int n_in,
                              void* d_out, int out_size, void* d_ws, size_t ws_size,
                              hipStream_t stream) {
    const int* src = (const int*)d_in[0];
    const int* dst = (const int*)d_in[1];
    const int* et  = (const int*)d_in[2];
    const float* emb    = (const float*)d_in[3];
    const float* bases1 = (const float*)d_in[4];
    const float* coef1  = (const float*)d_in[5];
    const float* wself1 = (const float*)d_in[6];
    const float* bias1  = (const float*)d_in[7];
    const float* bases2 = (const float*)d_in[8];
    const float* coef2  = (const float*)d_in[9];
    const float* wself2 = (const float*)d_in[10];
    const float* bias2  = (const float*)d_in[11];
    float* out = (float*)d_out;

    const int NE = in_sizes[0];
    const int NN = in_sizes[3] / DIM;
    const int NBKT = (NN + BKT_NODES - 1) / BKT_NODES;  // 782

    // Workspace: Wpk1|Wpk2|h1|hproj(9 planes)|bktpos|doff|dend|perm_tmp|perm  (~167 MB)
    unsigned short* Wpk1 = (unsigned short*)d_ws;
    unsigned short* Wpk2 = Wpk1 + (size_t)NW * DIM * DIM;
    float* h1 = (float*)(Wpk2 + (size_t)NW * DIM * DIM);
    unsigned short* hproj = (unsigned short*)(h1 + (size_t)NN * DIM);
    int* bktpos = (int*)(hproj + (size_t)NW * NN * DIM);
    int* doff = bktpos + MAXBKT;
    int* dend = doff + NN + 128;
    unsigned* perm_tmp = (unsigned*)(dend + NN + 128);
    unsigned* perm = perm_tmp + (size_t)NBKT * CAP;

    const int wpk_threads = 2 * NW * DIM * DIM;
    build_wpk2<<<(wpk_threads + 255) / 256, 256, 0, stream>>>(bases1, coef1, wself1, Wpk1,
                                                              bases2, coef2, wself2, Wpk2,
                                                              bktpos);

    partition2<<<(NE + P3_CHUNK - 1) / P3_CHUNK, 256, 0, stream>>>(src, dst, et, bktpos, perm_tmp, NE, NBKT);
    bucket_csr2<<<NBKT, 256, 0, stream>>>(perm_tmp, bktpos, perm, doff, dend, NN);

    const int proj_blocks = (NN + 63) / 64;
    const int gath_blocks = (NN + 3) / 4;  // one wave per dst

    // Layer 1
    proj_kernel<<<2 * proj_blocks, 256, 0, stream>>>(emb, Wpk1, hproj, NN, proj_blocks);
    gather8<<<gath_blocks, 256, 0, stream>>>(perm, doff, dend, hproj, bias1, h1, NN);

    // Layer 2
    proj_kernel<<<2 * proj_blocks, 256, 0, stream>>>(h1, Wpk2, hproj, NN, proj_blocks);
    gather8<<<gath_blocks, 256, 0, stream>>>(perm, doff, dend, hproj, bias2, out, NN);
}

// Round 13
// 157.942 us; speedup vs baseline: 7.3631x; 1.1780x over previous
//
#include <hip/hip_runtime.h>
#include <hip/hip_bf16.h>

#define DIM 64
#define NRELS 8
#define NBASES 4
#define KTOT 576          // 8*64 relation cols + 64 self cols
#define KCH 18            // KTOT / 32 MFMA k-chunks
#define LDSPAD 584        // tile row stride in ushorts (1168B: 16B-aligned, spreads banks)
#define BKT_SHIFT 7
#define BKT_NODES 128
#define MAXBKT 1024
#define CAP 4096
#define P3_CHUNK 4096

typedef __attribute__((ext_vector_type(8))) short short8;
typedef __attribute__((ext_vector_type(4))) float f32x4;

__device__ inline unsigned short f2bf(float f) {
    union { float f; unsigned int u; } v; v.f = f;
    unsigned int u = v.u;
    unsigned int r = u + 0x7FFFu + ((u >> 16) & 1u);
    return (unsigned short)(r >> 16);
}
__device__ inline float bf2f(unsigned short s) {
    union { unsigned int u; float f; } v; v.u = ((unsigned int)s) << 16;
    return v.f;
}

// Pack Wcat [576][64] for both layers into MFMA B-fragment order (bf16):
//   k < 512: rel = k>>6, i = k&63 -> sum_b coef[rel][b]*bases[b][i][j]
//   k >= 512: wself[k-512][j]
// Wpk[((ch*4 + jt)*64 + lane)*8 + e] = W[ch*32 + (lane>>4)*8 + e][jt*16 + (lane&15)]
// Also zero-inits bktpos.
__global__ void build_wpk3(const float* __restrict__ bases1, const float* __restrict__ coef1,
                           const float* __restrict__ wself1, unsigned short* __restrict__ Wpk1,
                           const float* __restrict__ bases2, const float* __restrict__ coef2,
                           const float* __restrict__ wself2, unsigned short* __restrict__ Wpk2,
                           int* __restrict__ bktpos) {
    int idx = blockIdx.x * blockDim.x + threadIdx.x;
    if (idx < MAXBKT) bktpos[idx] = 0;
    if (idx >= 2 * KTOT * DIM) return;
    int set = (idx >= KTOT * DIM);
    const float* bases = set ? bases2 : bases1;
    const float* coef  = set ? coef2 : coef1;
    const float* wself = set ? wself2 : wself1;
    unsigned short* Wpk = set ? Wpk2 : Wpk1;
    idx -= set * KTOT * DIM;
    int k = idx >> 6;          // 0..575
    int j = idx & 63;
    float v;
    if (k < 512) {
        int rel = k >> 6, i = k & 63;
        v = 0.f;
#pragma unroll
        for (int b = 0; b < NBASES; ++b)
            v += coef[rel * NBASES + b] * bases[((size_t)b * DIM + i) * DIM + j];
    } else {
        v = wself[(k - 512) * DIM + j];
    }
    int ch = k >> 5, within = k & 31, lhi = within >> 3, e = within & 7;
    int jt = j >> 4, lane = lhi * 16 + (j & 15);
    Wpk[(size_t)(((ch * 4 + jt) * 64 + lane) * 8 + e)] = f2bf(v);
}

// Cast f32 -> bf16, 8 elems/thread
__global__ __launch_bounds__(256) void cast_bf16(const float* __restrict__ in,
                                                 unsigned short* __restrict__ out, int n8) {
    int i = blockIdx.x * blockDim.x + threadIdx.x;
    if (i >= n8) return;
    const float4* p = (const float4*)(in + (size_t)i * 8);
    float4 a = p[0], b = p[1];
    uint4 v;
    v.x = (unsigned)f2bf(a.x) | ((unsigned)f2bf(a.y) << 16);
    v.y = (unsigned)f2bf(a.z) | ((unsigned)f2bf(a.w) << 16);
    v.z = (unsigned)f2bf(b.x) | ((unsigned)f2bf(b.y) << 16);
    v.w = (unsigned)f2bf(b.z) | ((unsigned)f2bf(b.w) << 16);
    *(uint4*)(out + (size_t)i * 8) = v;
}

// Partition edges into fixed-stride buckets, packed src | et<<17 | dstlow<<20.
__global__ __launch_bounds__(256) void partition2(const int* __restrict__ src,
                                                  const int* __restrict__ dst,
                                                  const int* __restrict__ et,
                                                  int* __restrict__ bktpos,
                                                  unsigned* __restrict__ perm_tmp,
                                                  int n_edges, int nbkt) {
    __shared__ int h[MAXBKT];
    __shared__ int base[MAXBKT];
    int t = threadIdx.x;
    for (int i = t; i < nbkt; i += 256) h[i] = 0;
    __syncthreads();
    int e0 = blockIdx.x * P3_CHUNK;
#pragma unroll
    for (int k = 0; k < P3_CHUNK / 256; ++k) {
        int e = e0 + k * 256 + t;
        if (e < n_edges) atomicAdd(&h[dst[e] >> BKT_SHIFT], 1);
    }
    __syncthreads();
    for (int i = t; i < nbkt; i += 256) {
        int c = h[i];
        base[i] = c ? atomicAdd(&bktpos[i], c) : 0;
        h[i] = 0;
    }
    __syncthreads();
#pragma unroll
    for (int k = 0; k < P3_CHUNK / 256; ++k) {
        int e = e0 + k * 256 + t;
        if (e < n_edges) {
            int d = dst[e];
            int bk = d >> BKT_SHIFT;
            int rk = atomicAdd(&h[bk], 1);
            perm_tmp[(size_t)bk * CAP + base[bk] + rk] =
                (unsigned)src[e] | ((unsigned)et[e] << 17) | ((unsigned)(d & (BKT_NODES - 1)) << 20);
        }
    }
}

// One block per bucket: sort by 10-bit key (dstlow*8 + rel). Emits per-(dst,rel)
// segment starts seg[node*8+r], per-dst end dend[node], and perm = src (17 bits).
__global__ __launch_bounds__(256) void bucket_csr3(const unsigned* __restrict__ perm_tmp,
                                                   const int* __restrict__ bktpos,
                                                   unsigned* __restrict__ perm,
                                                   int* __restrict__ seg, int* __restrict__ dend,
                                                   int n_nodes) {
    __shared__ int h[1024];
    __shared__ int ex[1024];
    __shared__ int wtot[4];
    const int t = threadIdx.x;
    const int b = blockIdx.x;
    const int cnt = bktpos[b];
    const size_t bb = (size_t)b * CAP;
    for (int i = t; i < 1024; i += 256) h[i] = 0;
    __syncthreads();
    for (int i = t; i < cnt; i += 256) atomicAdd(&h[(perm_tmp[bb + i] >> 17) & 1023], 1);
    __syncthreads();
    int v0 = h[4 * t], v1 = h[4 * t + 1], v2 = h[4 * t + 2], v3 = h[4 * t + 3];
    int s = v0 + v1 + v2 + v3;
    int lane = t & 63, w = t >> 6;
    int x = s;
#pragma unroll
    for (int ofs = 1; ofs < 64; ofs <<= 1) {
        int y = __shfl_up(x, ofs);
        if (lane >= ofs) x += y;
    }
    if (lane == 63) wtot[w] = x;
    __syncthreads();
    int woff = 0;
    for (int k = 0; k < w; ++k) woff += wtot[k];
    int run = woff + x - s;
    ex[4 * t] = run; run += v0;
    ex[4 * t + 1] = run; run += v1;
    ex[4 * t + 2] = run; run += v2;
    ex[4 * t + 3] = run;
    __syncthreads();
    for (int k = t; k < 1024; k += 256) {
        int node = b * BKT_NODES + (k >> 3);
        if (node < n_nodes) {
            seg[(size_t)node * 8 + (k & 7)] = b * CAP + ex[k];
            if ((k & 7) == 7) dend[node] = b * CAP + ((k == 1023) ? cnt : ex[k + 1]);
        }
    }
    __syncthreads();
    for (int i = t; i < cnt; i += 256) {
        unsigned rc = perm_tmp[bb + i];
        int p = atomicAdd(&ex[(rc >> 17) & 1023], 1);
        perm[bb + p] = rc & 0x1FFFFu;  // src only
    }
}

// Fused aggregate + project: 16 dst per block (4 waves x 4 dst).
// Per dst: 16 lanes = 2 edge-slots x 8 col-octets. Per-relation register
// aggregation of raw h_bf16 rows (12.8MB L2/L3-resident table), staged as a
// [16][576] bf16 A-tile in LDS, then K=576 MFMA chain vs packed Wcat.
// Perm prefetch goes through LDS (NOT register shuffle: __shfl inside the
// divergent edge loop reads inactive lanes -> returns 0 on CDNA -> was the
// round-12 correctness bug).
template <bool OUT_F32>
__global__ __launch_bounds__(256) void rgcn_fused(const unsigned* __restrict__ perm,
                                                  const int* __restrict__ seg,
                                                  const int* __restrict__ dend,
                                                  const unsigned short* __restrict__ hbf,
                                                  const unsigned short* __restrict__ Wpk,
                                                  const float* __restrict__ bias,
                                                  float* __restrict__ out32,
                                                  unsigned short* __restrict__ outbf,
                                                  int n_nodes) {
    __shared__ unsigned short tile[16 * LDSPAD];
    __shared__ unsigned plds[16][16];   // prefetched perm entries per local dst
    const int lane = threadIdx.x & 63;
    const int wave = threadIdx.x >> 6;
    const int d0 = blockIdx.x * 16;
    const int di = lane >> 4;          // dst within wave (0..3)
    const int ld = wave * 4 + di;      // local dst row (0..15)
    const int d = d0 + ld;
    const int slot = (lane >> 3) & 1;  // edge slot
    const int s = lane & 7;            // col octet
    const int il = lane & 15;
    const bool valid = d < n_nodes;
    const int dc = valid ? d : 0;

    // per-lane segment bounds: il<8 -> seg[d*8+il], il==8 -> dend[d]
    int rbv = 0;
    if (valid) rbv = (il < 8) ? seg[(size_t)dc * 8 + il] : dend[dc];
    const int beg = __shfl(rbv, (di << 4));       // converged here: safe
    const int dv  = __shfl(rbv, (di << 4) + 8);

    // prefetch up to 16 perm entries for this dst into LDS (exec-mask-safe reads later)
    unsigned pvv = 0u;
    if (valid && beg + il < dv) pvv = perm[beg + il];
    plds[ld][il] = pvv;

    // self row -> tile cols 512..575 (slot-1 lanes, direct bf16 copy)
    if (slot == 1) {
        uint4 v = make_uint4(0u, 0u, 0u, 0u);
        if (valid) v = *(const uint4*)(hbf + (size_t)dc * DIM + s * 8);
        *(uint4*)&tile[ld * LDSPAD + 512 + s * 8] = v;
    }

#pragma unroll
    for (int rel = 0; rel < NRELS; ++rel) {
        int rb = __shfl(rbv, (di << 4) + rel);        // converged at loop top: safe
        int re = (rel < 7) ? __shfl(rbv, (di << 4) + rel + 1) : dv;
        float a0 = 0.f, a1 = 0.f, a2 = 0.f, a3 = 0.f, a4 = 0.f, a5 = 0.f, a6 = 0.f, a7 = 0.f;
        for (int e = rb + slot; e < re; e += 2) {
            int roff = e - beg;
            unsigned rc = (roff < 16) ? plds[ld][roff] : perm[e];  // LDS read: divergence-safe
            uint4 v = *(const uint4*)(hbf + (size_t)rc * DIM + s * 8);
            a0 += bf2f((unsigned short)(v.x & 0xFFFFu)); a1 += bf2f((unsigned short)(v.x >> 16));
            a2 += bf2f((unsigned short)(v.y & 0xFFFFu)); a3 += bf2f((unsigned short)(v.y >> 16));
            a4 += bf2f((unsigned short)(v.z & 0xFFFFu)); a5 += bf2f((unsigned short)(v.z >> 16));
            a6 += bf2f((unsigned short)(v.w & 0xFFFFu)); a7 += bf2f((unsigned short)(v.w >> 16));
        }
        a0 += __shfl_xor(a0, 8); a1 += __shfl_xor(a1, 8);   // converged after loop: safe
        a2 += __shfl_xor(a2, 8); a3 += __shfl_xor(a3, 8);
        a4 += __shfl_xor(a4, 8); a5 += __shfl_xor(a5, 8);
        a6 += __shfl_xor(a6, 8); a7 += __shfl_xor(a7, 8);
        if (slot == 0) {
            uint4 v;
            v.x = (unsigned)f2bf(a0) | ((unsigned)f2bf(a1) << 16);
            v.y = (unsigned)f2bf(a2) | ((unsigned)f2bf(a3) << 16);
            v.z = (unsigned)f2bf(a4) | ((unsigned)f2bf(a5) << 16);
            v.w = (unsigned)f2bf(a6) | ((unsigned)f2bf(a7) << 16);
            *(uint4*)&tile[ld * LDSPAD + rel * 64 + s * 8] = v;
        }
    }
    __syncthreads();

    // MFMA phase: wave = output col quadrant jt; A rows = 16 dst, K = 576.
    const int lrow = lane & 15;
    const int lhi = lane >> 4;
    f32x4 c = {0.f, 0.f, 0.f, 0.f};
#pragma unroll
    for (int ch = 0; ch < KCH; ++ch) {
        short8 af = *(const short8*)&tile[lrow * LDSPAD + ch * 32 + lhi * 8];
        short8 bfr = *(const short8*)(Wpk + (size_t)(((ch * 4 + wave) * 64 + lane) * 8));
        c = __builtin_amdgcn_mfma_f32_16x16x32_bf16(af, bfr, c, 0, 0, 0);
    }
    const int col = wave * 16 + lrow;
    const float bj = bias[col];
#pragma unroll
    for (int reg = 0; reg < 4; ++reg) {
        int rr = lhi * 4 + reg;
        int dd = d0 + rr;
        if (dd < n_nodes) {
            float val = c[reg] + bj;
            if (OUT_F32) out32[(size_t)dd * DIM + col] = val;
            else outbf[(size_t)dd * DIM + col] = f2bf(val);
        }
    }
}

extern "C" void kernel_launch(void* const* d_in, const int* in_sizes, int n_in,
                              void* d_out, int out_size, void* d_ws, size_t ws_size,
                              hipStream_t stream) {
    const int* src = (const int*)d_in[0];
    const int* dst = (const int*)d_in[1];
    const int* et  = (const int*)d_in[2];
    const float* emb    = (const float*)d_in[3];
    const float* bases1 = (const float*)d_in[4];
    const float* coef1  = (const float*)d_in[5];
    const float* wself1 = (const float*)d_in[6];
    const float* bias1  = (const float*)d_in[7];
    const float* bases2 = (const float*)d_in[8];
    const float* coef2  = (const float*)d_in[9];
    const float* wself2 = (const float*)d_in[10];
    const float* bias2  = (const float*)d_in[11];
    float* out = (float*)d_out;

    const int NE = in_sizes[0];
    const int NN = in_sizes[3] / DIM;
    const int NBKT = (NN + BKT_NODES - 1) / BKT_NODES;  // 782

    // Workspace: Wpk1|Wpk2|embbf|h1bf|bktpos|seg|dend|perm_tmp|perm  (~56 MB)
    unsigned short* Wpk1 = (unsigned short*)d_ws;
    unsigned short* Wpk2 = Wpk1 + (size_t)KCH * 4 * 64 * 8;
    unsigned short* embbf = Wpk2 + (size_t)KCH * 4 * 64 * 8;
    unsigned short* h1bf = embbf + (size_t)NN * DIM;
    int* bktpos = (int*)(h1bf + (size_t)NN * DIM);
    int* seg = bktpos + MAXBKT;
    int* dend = seg + (size_t)NN * 8 + 64;
    unsigned* perm_tmp = (unsigned*)(dend + NN + 64);
    unsigned* perm = perm_tmp + (size_t)NBKT * CAP;

    const int wpk_threads = 2 * KTOT * DIM;
    build_wpk3<<<(wpk_threads + 255) / 256, 256, 0, stream>>>(bases1, coef1, wself1, Wpk1,
                                                              bases2, coef2, wself2, Wpk2,
                                                              bktpos);
    cast_bf16<<<(NN * 8 + 255) / 256, 256, 0, stream>>>(emb, embbf, NN * 8);

    partition2<<<(NE + P3_CHUNK - 1) / P3_CHUNK, 256, 0, stream>>>(src, dst, et, bktpos,
                                                                   perm_tmp, NE, NBKT);
    bucket_csr3<<<NBKT, 256, 0, stream>>>(perm_tmp, bktpos, perm, seg, dend, NN);

    const int fused_blocks = (NN + 15) / 16;

    // Layer 1: h1 (bf16) = RGCN(embbf)
    rgcn_fused<false><<<fused_blocks, 256, 0, stream>>>(perm, seg, dend, embbf, Wpk1, bias1,
                                                        nullptr, h1bf, NN);
    // Layer 2: out (f32) = RGCN(h1bf)
    rgcn_fused<true><<<fused_blocks, 256, 0, stream>>>(perm, seg, dend, h1bf, Wpk2, bias2,
                                                       out, nullptr, NN);
}

// Round 14
// 149.060 us; speedup vs baseline: 7.8018x; 1.0596x over previous
//
#include <hip/hip_runtime.h>
#include <hip/hip_bf16.h>

#define DIM 64
#define NRELS 8
#define NBASES 4
#define KTOT 576          // 8*64 relation cols + 64 self cols
#define KCH 18            // KTOT / 32 MFMA k-chunks
#define LDSPAD 584        // tile row stride in ushorts (1168B; 292 dwords ≡ 4 mod 32)
#define BKT_SHIFT 7
#define BKT_NODES 128
#define MAXBKT 1024
#define CAP 4096
#define P3_CHUNK 4096

typedef __attribute__((ext_vector_type(8))) short short8;
typedef __attribute__((ext_vector_type(4))) float f32x4;

__device__ inline unsigned short f2bf(float f) {
    union { float f; unsigned int u; } v; v.f = f;
    unsigned int u = v.u;
    unsigned int r = u + 0x7FFFu + ((u >> 16) & 1u);
    return (unsigned short)(r >> 16);
}
__device__ inline float bf2f(unsigned short s) {
    union { unsigned int u; float f; } v; v.u = ((unsigned int)s) << 16;
    return v.f;
}
// pack two f32 -> (bf16(lo) | bf16(hi)<<16) in one HW instruction (RNE)
__device__ inline unsigned cvtpk(float lo, float hi) {
    unsigned r;
    asm("v_cvt_pk_bf16_f32 %0, %1, %2" : "=v"(r) : "v"(lo), "v"(hi));
    return r;
}

// Pack Wcat [576][64] for both layers into MFMA B-fragment order (bf16). Zero-inits bktpos.
__global__ void build_wpk3(const float* __restrict__ bases1, const float* __restrict__ coef1,
                           const float* __restrict__ wself1, unsigned short* __restrict__ Wpk1,
                           const float* __restrict__ bases2, const float* __restrict__ coef2,
                           const float* __restrict__ wself2, unsigned short* __restrict__ Wpk2,
                           int* __restrict__ bktpos) {
    int idx = blockIdx.x * blockDim.x + threadIdx.x;
    if (idx < MAXBKT) bktpos[idx] = 0;
    if (idx >= 2 * KTOT * DIM) return;
    int set = (idx >= KTOT * DIM);
    const float* bases = set ? bases2 : bases1;
    const float* coef  = set ? coef2 : coef1;
    const float* wself = set ? wself2 : wself1;
    unsigned short* Wpk = set ? Wpk2 : Wpk1;
    idx -= set * KTOT * DIM;
    int k = idx >> 6;          // 0..575
    int j = idx & 63;
    float v;
    if (k < 512) {
        int rel = k >> 6, i = k & 63;
        v = 0.f;
#pragma unroll
        for (int b = 0; b < NBASES; ++b)
            v += coef[rel * NBASES + b] * bases[((size_t)b * DIM + i) * DIM + j];
    } else {
        v = wself[(k - 512) * DIM + j];
    }
    int ch = k >> 5, within = k & 31, lhi = within >> 3, e = within & 7;
    int jt = j >> 4, lane = lhi * 16 + (j & 15);
    Wpk[(size_t)(((ch * 4 + jt) * 64 + lane) * 8 + e)] = f2bf(v);
}

// Cast f32 -> bf16, 8 elems/thread
__global__ __launch_bounds__(256) void cast_bf16(const float* __restrict__ in,
                                                 unsigned short* __restrict__ out, int n8) {
    int i = blockIdx.x * blockDim.x + threadIdx.x;
    if (i >= n8) return;
    const float4* p = (const float4*)(in + (size_t)i * 8);
    float4 a = p[0], b = p[1];
    uint4 v;
    v.x = (unsigned)f2bf(a.x) | ((unsigned)f2bf(a.y) << 16);
    v.y = (unsigned)f2bf(a.z) | ((unsigned)f2bf(a.w) << 16);
    v.z = (unsigned)f2bf(b.x) | ((unsigned)f2bf(b.y) << 16);
    v.w = (unsigned)f2bf(b.z) | ((unsigned)f2bf(b.w) << 16);
    *(uint4*)(out + (size_t)i * 8) = v;
}

// Partition edges into fixed-stride buckets, packed src | et<<17 | dstlow<<20.
__global__ __launch_bounds__(256) void partition2(const int* __restrict__ src,
                                                  const int* __restrict__ dst,
                                                  const int* __restrict__ et,
                                                  int* __restrict__ bktpos,
                                                  unsigned* __restrict__ perm_tmp,
                                                  int n_edges, int nbkt) {
    __shared__ int h[MAXBKT];
    __shared__ int base[MAXBKT];
    int t = threadIdx.x;
    for (int i = t; i < nbkt; i += 256) h[i] = 0;
    __syncthreads();
    int e0 = blockIdx.x * P3_CHUNK;
#pragma unroll
    for (int k = 0; k < P3_CHUNK / 256; ++k) {
        int e = e0 + k * 256 + t;
        if (e < n_edges) atomicAdd(&h[dst[e] >> BKT_SHIFT], 1);
    }
    __syncthreads();
    for (int i = t; i < nbkt; i += 256) {
        int c = h[i];
        base[i] = c ? atomicAdd(&bktpos[i], c) : 0;
        h[i] = 0;
    }
    __syncthreads();
#pragma unroll
    for (int k = 0; k < P3_CHUNK / 256; ++k) {
        int e = e0 + k * 256 + t;
        if (e < n_edges) {
            int d = dst[e];
            int bk = d >> BKT_SHIFT;
            int rk = atomicAdd(&h[bk], 1);
            perm_tmp[(size_t)bk * CAP + base[bk] + rk] =
                (unsigned)src[e] | ((unsigned)et[e] << 17) | ((unsigned)(d & (BKT_NODES - 1)) << 20);
        }
    }
}

// One block per bucket: sort by 10-bit key (dstlow*8 + rel). Emits per-(dst,rel)
// segment starts seg[node*8+r], per-dst end dend[node], and perm = src (17 bits).
__global__ __launch_bounds__(256) void bucket_csr3(const unsigned* __restrict__ perm_tmp,
                                                   const int* __restrict__ bktpos,
                                                   unsigned* __restrict__ perm,
                                                   int* __restrict__ seg, int* __restrict__ dend,
                                                   int n_nodes) {
    __shared__ int h[1024];
    __shared__ int ex[1024];
    __shared__ int wtot[4];
    const int t = threadIdx.x;
    const int b = blockIdx.x;
    const int cnt = bktpos[b];
    const size_t bb = (size_t)b * CAP;
    for (int i = t; i < 1024; i += 256) h[i] = 0;
    __syncthreads();
    for (int i = t; i < cnt; i += 256) atomicAdd(&h[(perm_tmp[bb + i] >> 17) & 1023], 1);
    __syncthreads();
    int v0 = h[4 * t], v1 = h[4 * t + 1], v2 = h[4 * t + 2], v3 = h[4 * t + 3];
    int s = v0 + v1 + v2 + v3;
    int lane = t & 63, w = t >> 6;
    int x = s;
#pragma unroll
    for (int ofs = 1; ofs < 64; ofs <<= 1) {
        int y = __shfl_up(x, ofs);
        if (lane >= ofs) x += y;
    }
    if (lane == 63) wtot[w] = x;
    __syncthreads();
    int woff = 0;
    for (int k = 0; k < w; ++k) woff += wtot[k];
    int run = woff + x - s;
    ex[4 * t] = run; run += v0;
    ex[4 * t + 1] = run; run += v1;
    ex[4 * t + 2] = run; run += v2;
    ex[4 * t + 3] = run;
    __syncthreads();
    for (int k = t; k < 1024; k += 256) {
        int node = b * BKT_NODES + (k >> 3);
        if (node < n_nodes) {
            seg[(size_t)node * 8 + (k & 7)] = b * CAP + ex[k];
            if ((k & 7) == 7) dend[node] = b * CAP + ((k == 1023) ? cnt : ex[k + 1]);
        }
    }
    __syncthreads();
    for (int i = t; i < cnt; i += 256) {
        unsigned rc = perm_tmp[bb + i];
        int p = atomicAdd(&ex[(rc >> 17) & 1023], 1);
        perm[bb + p] = rc & 0x1FFFFu;  // src only
    }
}

// Fused aggregate + project: 16 dst per block (4 waves x 4 dst).
// Per dst: 16 lanes = 2 rel-slots x 8 col-octets. Slot 0 owns rels {0,2,4,6},
// slot 1 owns {1,3,5,7}: each lane accumulates a complete (dst,rel,octet)
// partial -> NO cross-lane reduce, pack via v_cvt_pk_bf16_f32.
// A-tile [16][576] bf16 in LDS, then K=576 MFMA chain vs packed Wcat.
template <bool OUT_F32>
__global__ __launch_bounds__(256) void rgcn_fused(const unsigned* __restrict__ perm,
                                                  const int* __restrict__ seg,
                                                  const int* __restrict__ dend,
                                                  const unsigned short* __restrict__ hbf,
                                                  const unsigned short* __restrict__ Wpk,
                                                  const float* __restrict__ bias,
                                                  float* __restrict__ out32,
                                                  unsigned short* __restrict__ outbf,
                                                  int n_nodes) {
    __shared__ unsigned short tile[16 * LDSPAD];
    __shared__ unsigned plds[16][16];   // prefetched perm entries per local dst
    const int lane = threadIdx.x & 63;
    const int wave = threadIdx.x >> 6;
    const int d0 = blockIdx.x * 16;
    const int di = lane >> 4;          // dst within wave (0..3)
    const int ld = wave * 4 + di;      // local dst row (0..15)
    const int d = d0 + ld;
    const int slot = (lane >> 3) & 1;  // rel parity slot
    const int s = lane & 7;            // col octet
    const int il = lane & 15;
    const bool valid = d < n_nodes;
    const int dc = valid ? d : 0;

    // per-lane segment bounds: il<8 -> seg[d*8+il], il==8 -> dend[d]
    int rbv = 0;
    if (valid) rbv = (il < 8) ? seg[(size_t)dc * 8 + il] : dend[dc];
    const int beg = __shfl(rbv, (di << 4));       // converged: safe
    const int dv  = __shfl(rbv, (di << 4) + 8);

    // prefetch up to 16 perm entries for this dst into LDS (divergence-safe reads later)
    unsigned pvv = 0u;
    if (valid && beg + il < dv) pvv = perm[beg + il];
    plds[ld][il] = pvv;

    // self row -> tile cols 512..575 (slot-1 lanes, direct bf16 copy)
    if (slot == 1) {
        uint4 v = make_uint4(0u, 0u, 0u, 0u);
        if (valid) v = *(const uint4*)(hbf + (size_t)dc * DIM + s * 8);
        *(uint4*)&tile[ld * LDSPAD + 512 + s * 8] = v;
    }

#pragma unroll
    for (int rp = 0; rp < 4; ++rp) {
        const int rel = rp * 2 + slot;  // slot 0: 0,2,4,6; slot 1: 1,3,5,7
        int rb = __shfl(rbv, (di << 4) + rel);                       // converged: safe
        int re = __shfl(rbv, (di << 4) + ((rel < 7) ? rel + 1 : 8)); // rel7 end = dend
        float a0 = 0.f, a1 = 0.f, a2 = 0.f, a3 = 0.f, a4 = 0.f, a5 = 0.f, a6 = 0.f, a7 = 0.f;
        for (int e = rb; e < re; ++e) {
            int roff = e - beg;
            unsigned rc = (roff < 16) ? plds[ld][roff] : perm[e];  // LDS read: divergence-safe
            uint4 v = *(const uint4*)(hbf + (size_t)rc * DIM + s * 8);
            a0 += bf2f((unsigned short)(v.x & 0xFFFFu)); a1 += bf2f((unsigned short)(v.x >> 16));
            a2 += bf2f((unsigned short)(v.y & 0xFFFFu)); a3 += bf2f((unsigned short)(v.y >> 16));
            a4 += bf2f((unsigned short)(v.z & 0xFFFFu)); a5 += bf2f((unsigned short)(v.z >> 16));
            a6 += bf2f((unsigned short)(v.w & 0xFFFFu)); a7 += bf2f((unsigned short)(v.w >> 16));
        }
        uint4 v;
        v.x = cvtpk(a0, a1);
        v.y = cvtpk(a2, a3);
        v.z = cvtpk(a4, a5);
        v.w = cvtpk(a6, a7);
        *(uint4*)&tile[ld * LDSPAD + rel * 64 + s * 8] = v;
    }
    __syncthreads();

    // MFMA phase: wave = output col quadrant jt; A rows = 16 dst, K = 576.
    const int lrow = lane & 15;
    const int lhi = lane >> 4;
    f32x4 c = {0.f, 0.f, 0.f, 0.f};
#pragma unroll
    for (int ch = 0; ch < KCH; ++ch) {
        short8 af = *(const short8*)&tile[lrow * LDSPAD + ch * 32 + lhi * 8];
        short8 bfr = *(const short8*)(Wpk + (size_t)(((ch * 4 + wave) * 64 + lane) * 8));
        c = __builtin_amdgcn_mfma_f32_16x16x32_bf16(af, bfr, c, 0, 0, 0);
    }
    const int col = wave * 16 + lrow;
    const float bj = bias[col];
#pragma unroll
    for (int reg = 0; reg < 4; ++reg) {
        int rr = lhi * 4 + reg;
        int dd = d0 + rr;
        if (dd < n_nodes) {
            float val = c[reg] + bj;
            if (OUT_F32) out32[(size_t)dd * DIM + col] = val;
            else outbf[(size_t)dd * DIM + col] = f2bf(val);
        }
    }
}

extern "C" void kernel_launch(void* const* d_in, const int* in_sizes, int n_in,
                              void* d_out, int out_size, void* d_ws, size_t ws_size,
                              hipStream_t stream) {
    const int* src = (const int*)d_in[0];
    const int* dst = (const int*)d_in[1];
    const int* et  = (const int*)d_in[2];
    const float* emb    = (const float*)d_in[3];
    const float* bases1 = (const float*)d_in[4];
    const float* coef1  = (const float*)d_in[5];
    const float* wself1 = (const float*)d_in[6];
    const float* bias1  = (const float*)d_in[7];
    const float* bases2 = (const float*)d_in[8];
    const float* coef2  = (const float*)d_in[9];
    const float* wself2 = (const float*)d_in[10];
    const float* bias2  = (const float*)d_in[11];
    float* out = (float*)d_out;

    const int NE = in_sizes[0];
    const int NN = in_sizes[3] / DIM;
    const int NBKT = (NN + BKT_NODES - 1) / BKT_NODES;  // 782

    // Workspace: Wpk1|Wpk2|embbf|h1bf|bktpos|seg|dend|perm_tmp|perm  (~56 MB)
    unsigned short* Wpk1 = (unsigned short*)d_ws;
    unsigned short* Wpk2 = Wpk1 + (size_t)KCH * 4 * 64 * 8;
    unsigned short* embbf = Wpk2 + (size_t)KCH * 4 * 64 * 8;
    unsigned short* h1bf = embbf + (size_t)NN * DIM;
    int* bktpos = (int*)(h1bf + (size_t)NN * DIM);
    int* seg = bktpos + MAXBKT;
    int* dend = seg + (size_t)NN * 8 + 64;
    unsigned* perm_tmp = (unsigned*)(dend + NN + 64);
    unsigned* perm = perm_tmp + (size_t)NBKT * CAP;

    const int wpk_threads = 2 * KTOT * DIM;
    build_wpk3<<<(wpk_threads + 255) / 256, 256, 0, stream>>>(bases1, coef1, wself1, Wpk1,
                                                              bases2, coef2, wself2, Wpk2,
                                                              bktpos);
    cast_bf16<<<(NN * 8 + 255) / 256, 256, 0, stream>>>(emb, embbf, NN * 8);

    partition2<<<(NE + P3_CHUNK - 1) / P3_CHUNK, 256, 0, stream>>>(src, dst, et, bktpos,
                                                                   perm_tmp, NE, NBKT);
    bucket_csr3<<<NBKT, 256, 0, stream>>>(perm_tmp, bktpos, perm, seg, dend, NN);

    const int fused_blocks = (NN + 15) / 16;

    // Layer 1: h1 (bf16) = RGCN(embbf)
    rgcn_fused<false><<<fused_blocks, 256, 0, stream>>>(perm, seg, dend, embbf, Wpk1, bias1,
                                                        nullptr, h1bf, NN);
    // Layer 2: out (f32) = RGCN(h1bf)
    rgcn_fused<true><<<fused_blocks, 256, 0, stream>>>(perm, seg, dend, h1bf, Wpk2, bias2,
                                                       out, nullptr, NN);
}

// Round 15
// 141.112 us; speedup vs baseline: 8.2412x; 1.0563x over previous
//
#include <hip/hip_runtime.h>
#include <hip/hip_bf16.h>

#define DIM 64
#define NRELS 8
#define NBASES 4
#define KTOT 576          // 8*64 relation cols + 64 self cols
#define KCH 18            // KTOT / 32 MFMA k-chunks
#define LDSPAD 584        // tile row stride in ushorts (1168B; skews 16B slots per row)
#define BKT_SHIFT 7
#define BKT_NODES 128
#define MAXBKT 1024
#define CAP 4096
#define P3_CHUNK 4096

typedef __attribute__((ext_vector_type(8))) short short8;
typedef __attribute__((ext_vector_type(4))) float f32x4;

__device__ inline unsigned short f2bf(float f) {
    union { float f; unsigned int u; } v; v.f = f;
    unsigned int u = v.u;
    unsigned int r = u + 0x7FFFu + ((u >> 16) & 1u);
    return (unsigned short)(r >> 16);
}
__device__ inline float bf2f(unsigned short s) {
    union { unsigned int u; float f; } v; v.u = ((unsigned int)s) << 16;
    return v.f;
}
// pack two f32 -> (bf16(lo) | bf16(hi)<<16) in one HW instruction (RNE)
__device__ inline unsigned cvtpk(float lo, float hi) {
    unsigned r;
    asm("v_cvt_pk_bf16_f32 %0, %1, %2" : "=v"(r) : "v"(lo), "v"(hi));
    return r;
}

// Pack Wcat [576][64] for both layers into MFMA B-fragment order (bf16). Zero-inits bktpos.
__global__ void build_wpk3(const float* __restrict__ bases1, const float* __restrict__ coef1,
                           const float* __restrict__ wself1, unsigned short* __restrict__ Wpk1,
                           const float* __restrict__ bases2, const float* __restrict__ coef2,
                           const float* __restrict__ wself2, unsigned short* __restrict__ Wpk2,
                           int* __restrict__ bktpos) {
    int idx = blockIdx.x * blockDim.x + threadIdx.x;
    if (idx < MAXBKT) bktpos[idx] = 0;
    if (idx >= 2 * KTOT * DIM) return;
    int set = (idx >= KTOT * DIM);
    const float* bases = set ? bases2 : bases1;
    const float* coef  = set ? coef2 : coef1;
    const float* wself = set ? wself2 : wself1;
    unsigned short* Wpk = set ? Wpk2 : Wpk1;
    idx -= set * KTOT * DIM;
    int k = idx >> 6;          // 0..575
    int j = idx & 63;
    float v;
    if (k < 512) {
        int rel = k >> 6, i = k & 63;
        v = 0.f;
#pragma unroll
        for (int b = 0; b < NBASES; ++b)
            v += coef[rel * NBASES + b] * bases[((size_t)b * DIM + i) * DIM + j];
    } else {
        v = wself[(k - 512) * DIM + j];
    }
    int ch = k >> 5, within = k & 31, lhi = within >> 3, e = within & 7;
    int jt = j >> 4, lane = lhi * 16 + (j & 15);
    Wpk[(size_t)(((ch * 4 + jt) * 64 + lane) * 8 + e)] = f2bf(v);
}

// Cast f32 -> bf16, 8 elems/thread
__global__ __launch_bounds__(256) void cast_bf16(const float* __restrict__ in,
                                                 unsigned short* __restrict__ out, int n8) {
    int i = blockIdx.x * blockDim.x + threadIdx.x;
    if (i >= n8) return;
    const float4* p = (const float4*)(in + (size_t)i * 8);
    float4 a = p[0], b = p[1];
    uint4 v;
    v.x = (unsigned)f2bf(a.x) | ((unsigned)f2bf(a.y) << 16);
    v.y = (unsigned)f2bf(a.z) | ((unsigned)f2bf(a.w) << 16);
    v.z = (unsigned)f2bf(b.x) | ((unsigned)f2bf(b.y) << 16);
    v.w = (unsigned)f2bf(b.z) | ((unsigned)f2bf(b.w) << 16);
    *(uint4*)(out + (size_t)i * 8) = v;
}

// Partition edges into fixed-stride buckets, packed src | et<<17 | dstlow<<20.
__global__ __launch_bounds__(256) void partition2(const int* __restrict__ src,
                                                  const int* __restrict__ dst,
                                                  const int* __restrict__ et,
                                                  int* __restrict__ bktpos,
                                                  unsigned* __restrict__ perm_tmp,
                                                  int n_edges, int nbkt) {
    __shared__ int h[MAXBKT];
    __shared__ int base[MAXBKT];
    int t = threadIdx.x;
    for (int i = t; i < nbkt; i += 256) h[i] = 0;
    __syncthreads();
    int e0 = blockIdx.x * P3_CHUNK;
#pragma unroll
    for (int k = 0; k < P3_CHUNK / 256; ++k) {
        int e = e0 + k * 256 + t;
        if (e < n_edges) atomicAdd(&h[dst[e] >> BKT_SHIFT], 1);
    }
    __syncthreads();
    for (int i = t; i < nbkt; i += 256) {
        int c = h[i];
        base[i] = c ? atomicAdd(&bktpos[i], c) : 0;
        h[i] = 0;
    }
    __syncthreads();
#pragma unroll
    for (int k = 0; k < P3_CHUNK / 256; ++k) {
        int e = e0 + k * 256 + t;
        if (e < n_edges) {
            int d = dst[e];
            int bk = d >> BKT_SHIFT;
            int rk = atomicAdd(&h[bk], 1);
            perm_tmp[(size_t)bk * CAP + base[bk] + rk] =
                (unsigned)src[e] | ((unsigned)et[e] << 17) | ((unsigned)(d & (BKT_NODES - 1)) << 20);
        }
    }
}

// One block per bucket: sort by 10-bit key (dstlow*8 + rel). Emits per-(dst,rel)
// segment starts seg[node*8+r], per-dst end dend[node], and perm = src (17 bits).
__global__ __launch_bounds__(256) void bucket_csr3(const unsigned* __restrict__ perm_tmp,
                                                   const int* __restrict__ bktpos,
                                                   unsigned* __restrict__ perm,
                                                   int* __restrict__ seg, int* __restrict__ dend,
                                                   int n_nodes) {
    __shared__ int h[1024];
    __shared__ int ex[1024];
    __shared__ int wtot[4];
    const int t = threadIdx.x;
    const int b = blockIdx.x;
    const int cnt = bktpos[b];
    const size_t bb = (size_t)b * CAP;
    for (int i = t; i < 1024; i += 256) h[i] = 0;
    __syncthreads();
    for (int i = t; i < cnt; i += 256) atomicAdd(&h[(perm_tmp[bb + i] >> 17) & 1023], 1);
    __syncthreads();
    int v0 = h[4 * t], v1 = h[4 * t + 1], v2 = h[4 * t + 2], v3 = h[4 * t + 3];
    int s = v0 + v1 + v2 + v3;
    int lane = t & 63, w = t >> 6;
    int x = s;
#pragma unroll
    for (int ofs = 1; ofs < 64; ofs <<= 1) {
        int y = __shfl_up(x, ofs);
        if (lane >= ofs) x += y;
    }
    if (lane == 63) wtot[w] = x;
    __syncthreads();
    int woff = 0;
    for (int k = 0; k < w; ++k) woff += wtot[k];
    int run = woff + x - s;
    ex[4 * t] = run; run += v0;
    ex[4 * t + 1] = run; run += v1;
    ex[4 * t + 2] = run; run += v2;
    ex[4 * t + 3] = run;
    __syncthreads();
    for (int k = t; k < 1024; k += 256) {
        int node = b * BKT_NODES + (k >> 3);
        if (node < n_nodes) {
            seg[(size_t)node * 8 + (k & 7)] = b * CAP + ex[k];
            if ((k & 7) == 7) dend[node] = b * CAP + ((k == 1023) ? cnt : ex[k + 1]);
        }
    }
    __syncthreads();
    for (int i = t; i < cnt; i += 256) {
        unsigned rc = perm_tmp[bb + i];
        int p = atomicAdd(&ex[(rc >> 17) & 1023], 1);
        perm[bb + p] = rc & 0x1FFFFu;  // src only
    }
}

// Fused aggregate + project: 16 dst per block (4 waves x 4 dst).
// Per dst: 16 lanes = 2 rel-slots x 8 col-octets. Slot 0 owns rels {0,2,4,6},
// slot 1 owns {1,3,5,7}; edge loop 2-deep unrolled (2 independent row loads
// in flight). Pack via v_cvt_pk_bf16_f32; A-tile [16][576] bf16 in LDS, then
// K=576 MFMA chain vs packed Wcat.
template <bool OUT_F32>
__global__ __launch_bounds__(256) void rgcn_fused(const unsigned* __restrict__ perm,
                                                  const int* __restrict__ seg,
                                                  const int* __restrict__ dend,
                                                  const unsigned short* __restrict__ hbf,
                                                  const unsigned short* __restrict__ Wpk,
                                                  const float* __restrict__ bias,
                                                  float* __restrict__ out32,
                                                  unsigned short* __restrict__ outbf,
                                                  int n_nodes) {
    __shared__ unsigned short tile[16 * LDSPAD];
    __shared__ unsigned plds[16][16];   // prefetched perm entries per local dst
    const int lane = threadIdx.x & 63;
    const int wave = threadIdx.x >> 6;
    const int d0 = blockIdx.x * 16;
    const int di = lane >> 4;          // dst within wave (0..3)
    const int ld = wave * 4 + di;      // local dst row (0..15)
    const int d = d0 + ld;
    const int slot = (lane >> 3) & 1;  // rel parity slot
    const int s = lane & 7;            // col octet
    const int il = lane & 15;
    const bool valid = d < n_nodes;
    const int dc = valid ? d : 0;

    // per-lane segment bounds: il<8 -> seg[d*8+il], il==8 -> dend[d]
    int rbv = 0;
    if (valid) rbv = (il < 8) ? seg[(size_t)dc * 8 + il] : dend[dc];
    const int beg = __shfl(rbv, (di << 4));       // converged: safe
    const int dv  = __shfl(rbv, (di << 4) + 8);

    // prefetch up to 16 perm entries for this dst into LDS (divergence-safe reads later)
    unsigned pvv = 0u;
    if (valid && beg + il < dv) pvv = perm[beg + il];
    plds[ld][il] = pvv;

    // self row -> tile cols 512..575 (slot-1 lanes, direct bf16 copy)
    if (slot == 1) {
        uint4 v = make_uint4(0u, 0u, 0u, 0u);
        if (valid) v = *(const uint4*)(hbf + (size_t)dc * DIM + s * 8);
        *(uint4*)&tile[ld * LDSPAD + 512 + s * 8] = v;
    }

#pragma unroll
    for (int rp = 0; rp < 4; ++rp) {
        const int rel = rp * 2 + slot;  // slot 0: 0,2,4,6; slot 1: 1,3,5,7
        int rb = __shfl(rbv, (di << 4) + rel);                       // converged: safe
        int re = __shfl(rbv, (di << 4) + ((rel < 7) ? rel + 1 : 8)); // rel7 end = dend
        float a0 = 0.f, a1 = 0.f, a2 = 0.f, a3 = 0.f, a4 = 0.f, a5 = 0.f, a6 = 0.f, a7 = 0.f;
        int e = rb;
        for (; e + 1 < re; e += 2) {
            int r0 = e - beg, r1 = r0 + 1;
            unsigned rc0 = (r0 < 16) ? plds[ld][r0] : perm[e];      // LDS: divergence-safe
            unsigned rc1 = (r1 < 16) ? plds[ld][r1] : perm[e + 1];
            uint4 v = *(const uint4*)(hbf + (size_t)rc0 * DIM + s * 8);
            uint4 u = *(const uint4*)(hbf + (size_t)rc1 * DIM + s * 8);
            a0 += bf2f((unsigned short)(v.x & 0xFFFFu)); a1 += bf2f((unsigned short)(v.x >> 16));
            a2 += bf2f((unsigned short)(v.y & 0xFFFFu)); a3 += bf2f((unsigned short)(v.y >> 16));
            a4 += bf2f((unsigned short)(v.z & 0xFFFFu)); a5 += bf2f((unsigned short)(v.z >> 16));
            a6 += bf2f((unsigned short)(v.w & 0xFFFFu)); a7 += bf2f((unsigned short)(v.w >> 16));
            a0 += bf2f((unsigned short)(u.x & 0xFFFFu)); a1 += bf2f((unsigned short)(u.x >> 16));
            a2 += bf2f((unsigned short)(u.y & 0xFFFFu)); a3 += bf2f((unsigned short)(u.y >> 16));
            a4 += bf2f((unsigned short)(u.z & 0xFFFFu)); a5 += bf2f((unsigned short)(u.z >> 16));
            a6 += bf2f((unsigned short)(u.w & 0xFFFFu)); a7 += bf2f((unsigned short)(u.w >> 16));
        }
        if (e < re) {
            int r0 = e - beg;
            unsigned rc = (r0 < 16) ? plds[ld][r0] : perm[e];
            uint4 v = *(const uint4*)(hbf + (size_t)rc * DIM + s * 8);
            a0 += bf2f((unsigned short)(v.x & 0xFFFFu)); a1 += bf2f((unsigned short)(v.x >> 16));
            a2 += bf2f((unsigned short)(v.y & 0xFFFFu)); a3 += bf2f((unsigned short)(v.y >> 16));
            a4 += bf2f((unsigned short)(v.z & 0xFFFFu)); a5 += bf2f((unsigned short)(v.z >> 16));
            a6 += bf2f((unsigned short)(v.w & 0xFFFFu)); a7 += bf2f((unsigned short)(v.w >> 16));
        }
        uint4 v;
        v.x = cvtpk(a0, a1);
        v.y = cvtpk(a2, a3);
        v.z = cvtpk(a4, a5);
        v.w = cvtpk(a6, a7);
        *(uint4*)&tile[ld * LDSPAD + rel * 64 + s * 8] = v;
    }
    __syncthreads();

    // MFMA phase: wave = output col quadrant jt; A rows = 16 dst, K = 576.
    const int lrow = lane & 15;
    const int lhi = lane >> 4;
    f32x4 c = {0.f, 0.f, 0.f, 0.f};
#pragma unroll
    for (int ch = 0; ch < KCH; ++ch) {
        short8 af = *(const short8*)&tile[lrow * LDSPAD + ch * 32 + lhi * 8];
        short8 bfr = *(const short8*)(Wpk + (size_t)(((ch * 4 + wave) * 64 + lane) * 8));
        c = __builtin_amdgcn_mfma_f32_16x16x32_bf16(af, bfr, c, 0, 0, 0);
    }
    const int col = wave * 16 + lrow;
    const float bj = bias[col];
#pragma unroll
    for (int reg = 0; reg < 4; ++reg) {
        int rr = lhi * 4 + reg;
        int dd = d0 + rr;
        if (dd < n_nodes) {
            float val = c[reg] + bj;
            if (OUT_F32) out32[(size_t)dd * DIM + col] = val;
            else outbf[(size_t)dd * DIM + col] = f2bf(val);
        }
    }
}

extern "C" void kernel_launch(void* const* d_in, const int* in_sizes, int n_in,
                              void* d_out, int out_size, void* d_ws, size_t ws_size,
                              hipStream_t stream) {
    const int* src = (const int*)d_in[0];
    const int* dst = (const int*)d_in[1];
    const int* et  = (const int*)d_in[2];
    const float* emb    = (const float*)d_in[3];
    const float* bases1 = (const float*)d_in[4];
    const float* coef1  = (const float*)d_in[5];
    const float* wself1 = (const float*)d_in[6];
    const float* bias1  = (const float*)d_in[7];
    const float* bases2 = (const float*)d_in[8];
    const float* coef2  = (const float*)d_in[9];
    const float* wself2 = (const float*)d_in[10];
    const float* bias2  = (const float*)d_in[11];
    float* out = (float*)d_out;

    const int NE = in_sizes[0];
    const int NN = in_sizes[3] / DIM;
    const int NBKT = (NN + BKT_NODES - 1) / BKT_NODES;  // 782

    // Workspace: Wpk1|Wpk2|embbf|h1bf|bktpos|seg|dend|perm_tmp|perm  (~56 MB)
    unsigned short* Wpk1 = (unsigned short*)d_ws;
    unsigned short* Wpk2 = Wpk1 + (size_t)KCH * 4 * 64 * 8;
    unsigned short* embbf = Wpk2 + (size_t)KCH * 4 * 64 * 8;
    unsigned short* h1bf = embbf + (size_t)NN * DIM;
    int* bktpos = (int*)(h1bf + (size_t)NN * DIM);
    int* seg = bktpos + MAXBKT;
    int* dend = seg + (size_t)NN * 8 + 64;
    unsigned* perm_tmp = (unsigned*)(dend + NN + 64);
    unsigned* perm = perm_tmp + (size_t)NBKT * CAP;

    const int wpk_threads = 2 * KTOT * DIM;
    build_wpk3<<<(wpk_threads + 255) / 256, 256, 0, stream>>>(bases1, coef1, wself1, Wpk1,
                                                              bases2, coef2, wself2, Wpk2,
                                                              bktpos);
    cast_bf16<<<(NN * 8 + 255) / 256, 256, 0, stream>>>(emb, embbf, NN * 8);

    partition2<<<(NE + P3_CHUNK - 1) / P3_CHUNK, 256, 0, stream>>>(src, dst, et, bktpos,
                                                                   perm_tmp, NE, NBKT);
    bucket_csr3<<<NBKT, 256, 0, stream>>>(perm_tmp, bktpos, perm, seg, dend, NN);

    const int fused_blocks = (NN + 15) / 16;

    // Layer 1: h1 (bf16) = RGCN(embbf)
    rgcn_fused<false><<<fused_blocks, 256, 0, stream>>>(perm, seg, dend, embbf, Wpk1, bias1,
                                                        nullptr, h1bf, NN);
    // Layer 2: out (f32) = RGCN(h1bf)
    rgcn_fused<true><<<fused_blocks, 256, 0, stream>>>(perm, seg, dend, h1bf, Wpk2, bias2,
                                                       out, nullptr, NN);
}